// Round 8
// baseline (2232.665 us; speedup 1.0000x reference)
//
#include <hip/hip_runtime.h>

#define EPSBN 2e-5f

typedef __attribute__((ext_vector_type(8))) short short8v;
typedef __attribute__((ext_vector_type(4))) float f32x4;

__device__ inline unsigned short f2bf(float f) {
  unsigned u = __float_as_uint(f);
  unsigned r = (u + 0x7FFFu + ((u >> 16) & 1u)) >> 16;
  return (unsigned short)r;
}
__device__ inline float bf2f(unsigned short h) {
  return __uint_as_float(((unsigned)h) << 16);
}

// ---------------------------------------------------------------------------
// Padded x staging
// ---------------------------------------------------------------------------
constexpr int XPADL = 9984;
constexpr int XPADR = 14336;
constexpr int PROW = XPADL + 32768 + XPADR;  // 57088

__global__ __launch_bounds__(256) void pad_x_kernel(const float* __restrict__ x,
                                                    float* __restrict__ xp) {
  int i = blockIdx.x * 256 + threadIdx.x;
  if (i >= 8 * PROW) return;
  int b = i / PROW;
  int pos = i - b * PROW - XPADL;
  xp[i] = (pos >= 0 && pos < 32768) ? x[b * 32768 + pos] : 0.f;
}

// ---------------------------------------------------------------------------
// Lift conv K=79 (dilation 2^S, scale 1/2^S) + pool4 + BN-stats, templated S.
// ---------------------------------------------------------------------------
template <int S>
__global__ __launch_bounds__(256) void lift_pool2_kernel(
    const float* __restrict__ xp, const float* __restrict__ w1,
    float* __restrict__ y1, float* __restrict__ st) {
  constexpr int d = 1 << S;
  constexpr float inv = 1.f / (float)d;
  const int tile = blockIdx.x;
  const int c = blockIdx.y;
  const int b = blockIdx.z;
  const int l0 = tile * 4096;
  const int t = threadIdx.x;
  const int q = t & (d - 1);
  const int j = t >> S;
  const int base = l0 + q + ((j * 16) << S);
  const float* xrow = xp + b * PROW + XPADL;
  const float* wr = w1 + c * 79;

  float acc[16], win[16];
#pragma unroll
  for (int r = 0; r < 16; ++r) acc[r] = 0.f;
  int idx = base - 39 * d;
#pragma unroll
  for (int i = 0; i < 16; ++i) {
    win[i] = xrow[idx];
    idx += d;
  }
#pragma unroll
  for (int ko = 0; ko < 5; ++ko) {
#pragma unroll
    for (int kj = 0; kj < 16; ++kj) {
      const int k = ko * 16 + kj;
      const float wk = (k < 79) ? wr[k] : 0.f;
#pragma unroll
      for (int r = 0; r < 16; ++r)
        acc[r] = fmaf(wk, win[(kj + r) & 15], acc[r]);
      win[kj] = xrow[idx];
      idx += d;
    }
  }

  float ssum = 0.f, ssq = 0.f;
  float* yrow = y1 + (((size_t)b * 51 + c) * 9 + S) * 8192 + (l0 >> 2);
  if constexpr (S == 0) {
#pragma unroll
    for (int m = 0; m < 4; ++m) {
      float v = fmaxf(fmaxf(acc[4 * m], acc[4 * m + 1]),
                      fmaxf(acc[4 * m + 2], acc[4 * m + 3]));
      yrow[4 * t + m] = v;
      ssum += v;
      ssq += v * v;
    }
  } else if constexpr (S == 1) {
#pragma unroll
    for (int m = 0; m < 8; ++m) {
      float u = fmaxf(acc[2 * m], acc[2 * m + 1]);
      u = fmaxf(u, __shfl_xor(u, 1));
      if ((t & 1) == 0) {
        float v = u * inv;
        yrow[8 * j + m] = v;
        ssum += v;
        ssq += v * v;
      }
    }
  } else {
#pragma unroll
    for (int r = 0; r < 16; ++r) {
      float u = fmaxf(acc[r], __shfl_xor(acc[r], 1));
      u = fmaxf(u, __shfl_xor(u, 2));
      if ((t & 3) == 0) {
        float v = u * inv;
        yrow[(q >> 2) + ((j * 16 + r) << (S - 2))] = v;
        ssum += v;
        ssq += v * v;
      }
    }
  }
#pragma unroll
  for (int off = 32; off > 0; off >>= 1) {
    ssum += __shfl_down(ssum, off);
    ssq += __shfl_down(ssq, off);
  }
  __shared__ float rs[4], rq[4];
  const int wid = t >> 6;
  if ((t & 63) == 0) {
    rs[wid] = ssum;
    rq[wid] = ssq;
  }
  __syncthreads();
  if (t == 0) {
    atomicAdd(&st[c], rs[0] + rs[1] + rs[2] + rs[3]);
    atomicAdd(&st[512 + c], rq[0] + rq[1] + rq[2] + rq[3]);
  }
}

// ---------------------------------------------------------------------------
// BN(train) + ReLU + pool4
// ---------------------------------------------------------------------------
__global__ __launch_bounds__(256) void bnrelu_pool_kernel(
    const float* __restrict__ Y, const float* __restrict__ st,
    const float* __restrict__ g, const float* __restrict__ bb,
    float* __restrict__ Z, int C, int H, int Lin, float invN,
    unsigned int total) {
  unsigned int idx = blockIdx.x * 256u + threadIdx.x;
  if (idx >= total) return;
  const unsigned int Lo = (unsigned int)(Lin >> 2);
  unsigned int lo = idx % Lo;
  unsigned int r1 = idx / Lo;
  unsigned int h = r1 % (unsigned int)H;
  unsigned int r2 = r1 / (unsigned int)H;
  unsigned int c = r2 % (unsigned int)C;
  unsigned int b = r2 / (unsigned int)C;
  float m = st[c] * invN;
  float v = st[512 + c] * invN - m * m;
  float sc = g[c] * rsqrtf(v + EPSBN);
  float bi = bb[c] - m * sc;
  const float* p = Y + (((size_t)b * C + c) * H + h) * Lin + 4u * lo;
  float a0 = p[0] * sc + bi, a1 = p[1] * sc + bi;
  float a2 = p[2] * sc + bi, a3 = p[3] * sc + bi;
  float r = fmaxf(fmaxf(a0, a1), fmaxf(a2, a3));
  Z[idx] = fmaxf(r, 0.f);
}

// ---------------------------------------------------------------------------
// BN(train) + ReLU, elementwise
// ---------------------------------------------------------------------------
__global__ __launch_bounds__(256) void bnrelu_kernel(
    const float* __restrict__ Y, const float* __restrict__ st,
    const float* __restrict__ g, const float* __restrict__ bb,
    float* __restrict__ A, int C, int HL, float invN, unsigned int total) {
  unsigned int idx = blockIdx.x * 256u + threadIdx.x;
  if (idx >= total) return;
  unsigned int c = (idx / (unsigned int)HL) % (unsigned int)C;
  float m = st[c] * invN;
  float v = st[512 + c] * invN - m * m;
  float sc = g[c] * rsqrtf(v + EPSBN);
  float bi = bb[c] - m * sc;
  A[idx] = fmaxf(fmaf(Y[idx], sc, bi), 0.f);
}

// ---------------------------------------------------------------------------
// Pack fp32 weights [Co][KTOT] -> split bf16: A_hi[COPAD][KPAD] followed by
// A_lo[COPAD][KPAD] (lo = bf16(v - hi)); zero-padded.
// ---------------------------------------------------------------------------
__global__ __launch_bounds__(256) void pack_w_kernel(
    const float* __restrict__ W, short* __restrict__ A, int Co, int KTOT,
    int KPAD, int COPAD) {
  int idx = blockIdx.x * 256 + threadIdx.x;
  if (idx >= COPAD * KPAD) return;
  int co = idx / KPAD, kk = idx - co * KPAD;
  float v = (co < Co && kk < KTOT) ? W[co * KTOT + kk] : 0.f;
  unsigned short hi = f2bf(v);
  unsigned short lo = f2bf(v - bf2f(hi));
  A[idx] = (short)hi;
  A[COPAD * KPAD + idx] = (short)lo;
}

// ---------------------------------------------------------------------------
// gg_mfma: split-precision bf16-MFMA GConvGG for the large stages.
// GEMM per (b,s): C[co,l] = sum_kk W[co,kk] * B[kk,l], kk=(ci,i,k).
// Operands decomposed v = hi + lo (bf16 each); per K-step 3 MFMAs:
// A_hi*B_hi + A_hi*B_lo + A_lo*B_hi (dropped lo*lo ~ 2^-18) => ~fp32 accuracy.
// B gathered from X on the fly (BN+ReLU+2^-(s+i)) into LDS hi/lo planes.
// Block = 4 waves x 16co, 32 l. MFMA 16x16x32 bf16 layouts (m89/m120):
// A[m=lane&15][k=quad*8+j], B[k][n=lane&15], D col=lane&15 row=quad*4+reg.
// Output stats (sum/sumsq per co) fused via quad shuffles + atomics.
// ---------------------------------------------------------------------------
template <int NKv>
__global__ __launch_bounds__(256) void gg_mfma_kernel(
    const float* __restrict__ X, const short* __restrict__ Apack,
    const float* __restrict__ stIn, const float* __restrict__ gIn,
    const float* __restrict__ bIn, float invNIn, float* __restrict__ Y,
    float* __restrict__ stOut, int Ci, int Co, int Hin, int L, int nL,
    int KTOT, int KPAD, int COPAD) {
  const int bx = blockIdx.x;
  const int lc = bx % nL;
  const int cog = bx / nL;
  const int s = blockIdx.y;
  const int b = blockIdx.z;
  const int Hout = Hin - NKv + 1;
  const int l0 = lc * 32;
  const int tid = threadIdx.x;
  const int lane = tid & 63;
  const int quad = lane >> 4;
  const int n0 = lane & 15;
  const int wv = tid >> 6;
  const int coBase = cog * 64 + wv * 16;

  __shared__ __align__(16) short Bh[32 * 72];
  __shared__ __align__(16) short Bl[32 * 72];
  __shared__ float insc[128], inbi[128];

  for (int c = tid; c < Ci; c += 256) {
    float sc = 1.f, bi = 0.f;
    if (stIn) {
      float m = stIn[c] * invNIn;
      float v = stIn[512 + c] * invNIn - m * m;
      sc = gIn[c] * rsqrtf(v + EPSBN);
      bi = bIn[c] - m * sc;
    }
    insc[c] = sc;
    inbi[c] = bi;
  }
  __syncthreads();

  f32x4 acc0 = {0.f, 0.f, 0.f, 0.f};
  f32x4 acc1 = {0.f, 0.f, 0.f, 0.f};
  const int coA = coBase + n0;
  const short* arowH = Apack + (size_t)coA * KPAD;
  const short* arowL = Apack + (size_t)COPAD * KPAD + (size_t)coA * KPAD;

  const int nch = (KTOT + 63) >> 6;
  const int lB = tid & 31;   // l within tile (staging)
  const int kkW = tid >> 5;  // kk stride-8 base (staging)

  for (int c0 = 0; c0 < nch; ++c0) {
    // ---- stage B chunk: 32 l x 64 kk, gathered + activated + split bf16
#pragma unroll
    for (int r = 0; r < 8; ++r) {
      const int kkL = kkW + r * 8;
      const int kk = (c0 << 6) + kkL;
      float v = 0.f;
      if (kk < KTOT) {
        const int ci = kk / (NKv * 3);
        const int rem = kk - ci * (NKv * 3);
        const int i = rem / 3;
        const int k = rem - 3 * i;
        const int dd = 1 << (s + i);
        const int pos = l0 + lB + (k - 1) * dd;
        if (pos >= 0 && pos < L) {
          float x = X[(((size_t)b * Ci + ci) * Hin + (s + i)) * L + pos];
          v = fmaxf(fmaf(x, insc[ci], inbi[ci]), 0.f) *
              __uint_as_float((unsigned)(127 - (s + i)) << 23);
        }
      }
      unsigned short hi = f2bf(v);
      unsigned short lo = f2bf(v - bf2f(hi));
      Bh[lB * 72 + kkL] = (short)hi;
      Bl[lB * 72 + kkL] = (short)lo;
    }
    __syncthreads();
    // ---- 2 K-steps of 32, 3 MFMAs each per acc
#pragma unroll
    for (int ks = 0; ks < 2; ++ks) {
      const int off = (c0 << 6) + ks * 32 + quad * 8;
      short8v ah = *(const short8v*)(arowH + off);
      short8v al = *(const short8v*)(arowL + off);
      const int bo = ks * 32 + quad * 8;
      short8v bh0 = *(const short8v*)(Bh + n0 * 72 + bo);
      short8v bl0 = *(const short8v*)(Bl + n0 * 72 + bo);
      short8v bh1 = *(const short8v*)(Bh + (16 + n0) * 72 + bo);
      short8v bl1 = *(const short8v*)(Bl + (16 + n0) * 72 + bo);
      acc0 = __builtin_amdgcn_mfma_f32_16x16x32_bf16(ah, bh0, acc0, 0, 0, 0);
      acc0 = __builtin_amdgcn_mfma_f32_16x16x32_bf16(ah, bl0, acc0, 0, 0, 0);
      acc0 = __builtin_amdgcn_mfma_f32_16x16x32_bf16(al, bh0, acc0, 0, 0, 0);
      acc1 = __builtin_amdgcn_mfma_f32_16x16x32_bf16(ah, bh1, acc1, 0, 0, 0);
      acc1 = __builtin_amdgcn_mfma_f32_16x16x32_bf16(ah, bl1, acc1, 0, 0, 0);
      acc1 = __builtin_amdgcn_mfma_f32_16x16x32_bf16(al, bh1, acc1, 0, 0, 0);
    }
    __syncthreads();
  }

  // ---- epilogue: store + fused stats
#pragma unroll
  for (int reg = 0; reg < 4; ++reg) {
    const int co = coBase + quad * 4 + reg;
    if (co < Co) {
      float* yp = Y + (((size_t)b * Co + co) * Hout + s) * L + l0;
      yp[n0] = acc0[reg];
      yp[16 + n0] = acc1[reg];
    }
  }
  if (stOut) {
#pragma unroll
    for (int reg = 0; reg < 4; ++reg) {
      float s1 = acc0[reg] + acc1[reg];
      float s2 = acc0[reg] * acc0[reg] + acc1[reg] * acc1[reg];
#pragma unroll
      for (int off = 1; off < 16; off <<= 1) {
        s1 += __shfl_xor(s1, off);
        s2 += __shfl_xor(s2, off);
      }
      const int co = coBase + quad * 4 + reg;
      if (n0 == 0 && co < Co) {
        atomicAdd(&stOut[co], s1);
        atomicAdd(&stOut[512 + co], s2);
      }
    }
  }
}

// ---------------------------------------------------------------------------
// gg_tail: no-LDS GConvGG for small stages (input pre-activated)
// ---------------------------------------------------------------------------
template <int NK, int L, int COSUB>
__global__ __launch_bounds__(256) void gg_tail_kernel(
    const float* __restrict__ X, const float* __restrict__ W,
    float* __restrict__ Y, float* __restrict__ stOut, int Ci, int Co,
    int Hin) {
  const int l = threadIdx.x % L;
  const int cs = threadIdx.x / L;
  const int co = blockIdx.x * COSUB + cs;
  const int s = blockIdx.y;
  const int b = blockIdx.z;
  const int Hout = Hin - NK + 1;

  float acc[NK];
#pragma unroll
  for (int i = 0; i < NK; ++i) acc[i] = 0.f;

  const float* wbase = W + (size_t)co * Ci * NK * 3;
  const float* xbase = X + ((size_t)b * Ci * Hin + s) * L;

  for (int ci = 0; ci < Ci; ++ci) {
    const float* wp = wbase + ci * (NK * 3);
    const float* xr = xbase + ci * (Hin * L);
#pragma unroll
    for (int i = 0; i < NK; ++i) {
      const int d = 1 << (s + i);
      const float* row = xr + i * L;
      float xm = (l >= d) ? row[l - d] : 0.f;
      float xc = row[l];
      float xp = (l + d < L) ? row[l + d] : 0.f;
      acc[i] = fmaf(wp[3 * i], xm,
                    fmaf(wp[3 * i + 1], xc, fmaf(wp[3 * i + 2], xp, acc[i])));
    }
  }
  float out = 0.f;
#pragma unroll
  for (int i = 0; i < NK; ++i) {
    float invd = __uint_as_float((unsigned)(127 - (s + i)) << 23);
    out = fmaf(acc[i], invd, out);
  }
  Y[(((size_t)b * Co + co) * Hout + s) * L + l] = out;

  float s1 = out, s2 = out * out;
  constexpr int RED = (L < 64) ? L : 64;
#pragma unroll
  for (int off = RED / 2; off > 0; off >>= 1) {
    s1 += __shfl_xor(s1, off);
    s2 += __shfl_xor(s2, off);
  }
  if ((threadIdx.x & (RED - 1)) == 0) {
    atomicAdd(&stOut[co], s1);
    atomicAdd(&stOut[512 + co], s2);
  }
}

// ---------------------------------------------------------------------------
// Final: bn10+relu, mean over L, classifier
// ---------------------------------------------------------------------------
__global__ __launch_bounds__(256) void final_kernel(
    const float* __restrict__ Y, const float* __restrict__ st,
    const float* __restrict__ g, const float* __restrict__ bb,
    const float* __restrict__ w11, float* __restrict__ out) {
  const int b = blockIdx.x;
  const int tid = threadIdx.x;
  __shared__ float tch[408];
  for (int c = tid; c < 408; c += 256) {
    float m = st[c] * (1.f / 256.f);
    float v = st[512 + c] * (1.f / 256.f) - m * m;
    float sc = g[c] * rsqrtf(v + EPSBN);
    float bi = bb[c] - m * sc;
    const float* p = Y + ((size_t)b * 408 + c) * 32;
    float ssum = 0.f;
#pragma unroll
    for (int l = 0; l < 32; ++l) ssum += fmaxf(p[l] * sc + bi, 0.f);
    tch[c] = ssum * (1.f / 32.f);
  }
  __syncthreads();
  if (tid < 10) {
    float ssum = 0.f;
    for (int c = 0; c < 408; ++c) ssum += w11[tid * 408 + c] * tch[c];
    out[b * 10 + tid] = ssum;
  }
}

// ---------------------------------------------------------------------------
extern "C" void kernel_launch(void* const* d_in, const int* in_sizes, int n_in,
                              void* d_out, int out_size, void* d_ws,
                              size_t ws_size, hipStream_t stream) {
  const float* x = (const float*)d_in[0];
  const float* w1 = (const float*)d_in[1];
  const float* w2 = (const float*)d_in[2];
  const float* w3 = (const float*)d_in[3];
  const float* w4 = (const float*)d_in[4];
  const float* w5 = (const float*)d_in[5];
  const float* w6 = (const float*)d_in[6];
  const float* w7 = (const float*)d_in[7];
  const float* w8 = (const float*)d_in[8];
  const float* w9 = (const float*)d_in[9];
  const float* w10 = (const float*)d_in[10];
  const float* w11 = (const float*)d_in[11];
  const float* gg[11];
  const float* bbv[11];
  for (int i = 1; i <= 10; ++i) {
    gg[i] = (const float*)d_in[12 + 2 * (i - 1)];
    bbv[i] = (const float*)d_in[12 + 2 * (i - 1) + 1];
  }

  float* ws = (float*)d_ws;
  const size_t AR0 = 0;
  const size_t AR1 = 30081024;
  const size_t STATS = 37601280;
  float* y1 = ws + AR0;
  float* xpad = ws + AR1;
  float* z1 = ws + AR1;
  float* y2 = ws + AR0;
  float* y3 = ws + AR0 + 5849088;
  float* z3 = ws + AR1;
  float* y4 = ws + AR0;
  float* y5 = ws + AR0 + 2088960;
  float* z5 = ws + AR1;
  float* a6 = ws + AR1 + 522240;
  float* a7 = ws + AR1 + 1148928;
  float* z8 = ws + AR1;
  float* a9 = ws + AR1 + 1775616;
  float* y6 = ws + AR0;
  float* y7 = ws + AR0 + 626688;
  float* y8 = ws + AR0 + 1253376;
  float* y9 = ws + AR0;
  float* y10 = ws + AR0 + 104448;
  // split-bf16 weight packs above live tensors in AR0 (y2/y3 <= 11.7M floats)
  short* apk2 = (short*)(ws + AR0 + 12000000);  // 64*512*2 shorts
  short* apk3 = apk2 + 64 * 512 * 2;            // 64*192*2
  short* apk4 = apk3 + 64 * 192 * 2;            // 128*512*2
  short* apk5 = apk4 + 128 * 512 * 2;           // 128*320*2
  float* st[11];
  for (int i = 1; i <= 10; ++i) st[i] = ws + STATS + (size_t)(i - 1) * 1024;

  hipMemsetAsync((void*)(ws + STATS), 0, 10 * 1024 * sizeof(float), stream);

  // ---- pad + lift (stats1 fused)
  pad_x_kernel<<<(8 * PROW + 255) / 256, 256, 0, stream>>>(x, xpad);
  {
    dim3 g(8, 51, 8);
    lift_pool2_kernel<0><<<g, 256, 0, stream>>>(xpad, w1, y1, st[1]);
    lift_pool2_kernel<1><<<g, 256, 0, stream>>>(xpad, w1, y1, st[1]);
    lift_pool2_kernel<2><<<g, 256, 0, stream>>>(xpad, w1, y1, st[1]);
    lift_pool2_kernel<3><<<g, 256, 0, stream>>>(xpad, w1, y1, st[1]);
    lift_pool2_kernel<4><<<g, 256, 0, stream>>>(xpad, w1, y1, st[1]);
    lift_pool2_kernel<5><<<g, 256, 0, stream>>>(xpad, w1, y1, st[1]);
    lift_pool2_kernel<6><<<g, 256, 0, stream>>>(xpad, w1, y1, st[1]);
    lift_pool2_kernel<7><<<g, 256, 0, stream>>>(xpad, w1, y1, st[1]);
    lift_pool2_kernel<8><<<g, 256, 0, stream>>>(xpad, w1, y1, st[1]);
  }
  {
    unsigned int tot = 8u * 51 * 9 * 2048;
    bnrelu_pool_kernel<<<(tot + 255) / 256, 256, 0, stream>>>(
        y1, st[1], gg[1], bbv[1], z1, 51, 9, 8192, 1.f / 589824.f, tot);
  }
  // ---- pack weights to split bf16 (y1 dead now; apk region free)
  pack_w_kernel<<<(64 * 512 + 255) / 256, 256, 0, stream>>>(w2, apk2, 51, 459,
                                                            512, 64);
  pack_w_kernel<<<(64 * 192 + 255) / 256, 256, 0, stream>>>(w3, apk3, 51, 153,
                                                            192, 64);
  pack_w_kernel<<<(128 * 512 + 255) / 256, 256, 0, stream>>>(w4, apk4, 102,
                                                             459, 512, 128);
  pack_w_kernel<<<(128 * 320 + 255) / 256, 256, 0, stream>>>(w5, apk5, 102,
                                                             306, 320, 128);
  // ---- gg2: 51->51, H 9->7, L=2048 (MFMA, stats fused)
  gg_mfma_kernel<3><<<dim3(64, 7, 8), 256, 0, stream>>>(
      z1, apk2, nullptr, nullptr, nullptr, 0.f, y2, st[2], 51, 51, 9, 2048,
      64, 459, 512, 64);
  // ---- gg3: 51->51, H7, L=2048 (bn2 on load, MFMA)
  gg_mfma_kernel<1><<<dim3(64, 7, 8), 256, 0, stream>>>(
      y2, apk3, st[2], gg[2], bbv[2], 1.f / 114688.f, y3, st[3], 51, 51, 7,
      2048, 64, 153, 192, 64);
  {
    unsigned int tot = 8u * 51 * 7 * 512;
    bnrelu_pool_kernel<<<(tot + 255) / 256, 256, 0, stream>>>(
        y3, st[3], gg[3], bbv[3], z3, 51, 7, 2048, 1.f / 114688.f, tot);
  }
  // ---- gg4: 51->102, H 7->5, L=512 (MFMA, 2 co-groups)
  gg_mfma_kernel<3><<<dim3(32, 5, 8), 256, 0, stream>>>(
      z3, apk4, nullptr, nullptr, nullptr, 0.f, y4, st[4], 51, 102, 7, 512,
      16, 459, 512, 128);
  // ---- gg5: 102->102, H5, L=512 (bn4 on load, MFMA)
  gg_mfma_kernel<1><<<dim3(32, 5, 8), 256, 0, stream>>>(
      y4, apk5, st[4], gg[4], bbv[4], 1.f / 20480.f, y5, st[5], 102, 102, 5,
      512, 16, 306, 320, 128);
  {
    unsigned int tot = 8u * 102 * 5 * 128;
    bnrelu_pool_kernel<<<(tot + 255) / 256, 256, 0, stream>>>(
        y5, st[5], gg[5], bbv[5], z5, 102, 5, 512, 1.f / 20480.f, tot);
  }
  // ---- gg6: 102->204, H 5->3, L=128
  gg_tail_kernel<3, 128, 2><<<dim3(102, 3, 8), 256, 0, stream>>>(
      z5, w6, y6, st[6], 102, 204, 5);
  {
    unsigned int tot = 8u * 204 * 3 * 128;
    bnrelu_kernel<<<(tot + 255) / 256, 256, 0, stream>>>(
        y6, st[6], gg[6], bbv[6], a6, 204, 3 * 128, 1.f / 3072.f, tot);
  }
  // ---- gg7: 204->204, H3, L=128
  gg_tail_kernel<1, 128, 2><<<dim3(102, 3, 8), 256, 0, stream>>>(
      a6, w7, y7, st[7], 204, 204, 3);
  {
    unsigned int tot = 8u * 204 * 3 * 128;
    bnrelu_kernel<<<(tot + 255) / 256, 256, 0, stream>>>(
        y7, st[7], gg[7], bbv[7], a7, 204, 3 * 128, 1.f / 3072.f, tot);
  }
  // ---- gg8: 204->204, H3, L=128
  gg_tail_kernel<1, 128, 2><<<dim3(102, 3, 8), 256, 0, stream>>>(
      a7, w8, y8, st[8], 204, 204, 3);
  {
    unsigned int tot = 8u * 204 * 3 * 32;
    bnrelu_pool_kernel<<<(tot + 255) / 256, 256, 0, stream>>>(
        y8, st[8], gg[8], bbv[8], z8, 204, 3, 128, 1.f / 3072.f, tot);
  }
  // ---- gg9: 204->408, H 3->1, L=32
  gg_tail_kernel<3, 32, 8><<<dim3(51, 1, 8), 256, 0, stream>>>(
      z8, w9, y9, st[9], 204, 408, 3);
  {
    unsigned int tot = 8u * 408 * 32;
    bnrelu_kernel<<<(tot + 255) / 256, 256, 0, stream>>>(
        y9, st[9], gg[9], bbv[9], a9, 408, 32, 1.f / 256.f, tot);
  }
  // ---- gg10: 408->408, H1, L=32
  gg_tail_kernel<1, 32, 8><<<dim3(51, 1, 8), 256, 0, stream>>>(
      a9, w10, y10, st[10], 408, 408, 1);
  // ---- final
  final_kernel<<<dim3(8), 256, 0, stream>>>(y10, st[10], gg[10], bbv[10], w11,
                                            (float*)d_out);
}

// Round 9
// 2015.392 us; speedup vs baseline: 1.1078x; 1.1078x over previous
//
#include <hip/hip_runtime.h>

#define EPSBN 2e-5f

typedef __attribute__((ext_vector_type(8))) short short8v;
typedef __attribute__((ext_vector_type(4))) float f32x4;

__device__ inline unsigned short f2bf(float f) {
  unsigned u = __float_as_uint(f);
  unsigned r = (u + 0x7FFFu + ((u >> 16) & 1u)) >> 16;
  return (unsigned short)r;
}
__device__ inline float bf2f(unsigned short h) {
  return __uint_as_float(((unsigned)h) << 16);
}

// ---------------------------------------------------------------------------
// Padded x staging
// ---------------------------------------------------------------------------
constexpr int XPADL = 9984;
constexpr int XPADR = 14336;
constexpr int PROW = XPADL + 32768 + XPADR;  // 57088

__global__ __launch_bounds__(256) void pad_x_kernel(const float* __restrict__ x,
                                                    float* __restrict__ xp) {
  int i = blockIdx.x * 256 + threadIdx.x;
  if (i >= 8 * PROW) return;
  int b = i / PROW;
  int pos = i - b * PROW - XPADL;
  xp[i] = (pos >= 0 && pos < 32768) ? x[b * 32768 + pos] : 0.f;
}

// ---------------------------------------------------------------------------
// Lift conv K=79 (dilation 2^S, scale 1/2^S) + pool4 + BN-stats, templated S.
// ---------------------------------------------------------------------------
template <int S>
__global__ __launch_bounds__(256) void lift_pool2_kernel(
    const float* __restrict__ xp, const float* __restrict__ w1,
    float* __restrict__ y1, float* __restrict__ st) {
  constexpr int d = 1 << S;
  constexpr float inv = 1.f / (float)d;
  const int tile = blockIdx.x;
  const int c = blockIdx.y;
  const int b = blockIdx.z;
  const int l0 = tile * 4096;
  const int t = threadIdx.x;
  const int q = t & (d - 1);
  const int j = t >> S;
  const int base = l0 + q + ((j * 16) << S);
  const float* xrow = xp + b * PROW + XPADL;
  const float* wr = w1 + c * 79;

  float acc[16], win[16];
#pragma unroll
  for (int r = 0; r < 16; ++r) acc[r] = 0.f;
  int idx = base - 39 * d;
#pragma unroll
  for (int i = 0; i < 16; ++i) {
    win[i] = xrow[idx];
    idx += d;
  }
#pragma unroll
  for (int ko = 0; ko < 5; ++ko) {
#pragma unroll
    for (int kj = 0; kj < 16; ++kj) {
      const int k = ko * 16 + kj;
      const float wk = (k < 79) ? wr[k] : 0.f;
#pragma unroll
      for (int r = 0; r < 16; ++r)
        acc[r] = fmaf(wk, win[(kj + r) & 15], acc[r]);
      win[kj] = xrow[idx];
      idx += d;
    }
  }

  float ssum = 0.f, ssq = 0.f;
  float* yrow = y1 + (((size_t)b * 51 + c) * 9 + S) * 8192 + (l0 >> 2);
  if constexpr (S == 0) {
#pragma unroll
    for (int m = 0; m < 4; ++m) {
      float v = fmaxf(fmaxf(acc[4 * m], acc[4 * m + 1]),
                      fmaxf(acc[4 * m + 2], acc[4 * m + 3]));
      yrow[4 * t + m] = v;
      ssum += v;
      ssq += v * v;
    }
  } else if constexpr (S == 1) {
#pragma unroll
    for (int m = 0; m < 8; ++m) {
      float u = fmaxf(acc[2 * m], acc[2 * m + 1]);
      u = fmaxf(u, __shfl_xor(u, 1));
      if ((t & 1) == 0) {
        float v = u * inv;
        yrow[8 * j + m] = v;
        ssum += v;
        ssq += v * v;
      }
    }
  } else {
#pragma unroll
    for (int r = 0; r < 16; ++r) {
      float u = fmaxf(acc[r], __shfl_xor(acc[r], 1));
      u = fmaxf(u, __shfl_xor(u, 2));
      if ((t & 3) == 0) {
        float v = u * inv;
        yrow[(q >> 2) + ((j * 16 + r) << (S - 2))] = v;
        ssum += v;
        ssq += v * v;
      }
    }
  }
#pragma unroll
  for (int off = 32; off > 0; off >>= 1) {
    ssum += __shfl_down(ssum, off);
    ssq += __shfl_down(ssq, off);
  }
  __shared__ float rs[4], rq[4];
  const int wid = t >> 6;
  if ((t & 63) == 0) {
    rs[wid] = ssum;
    rq[wid] = ssq;
  }
  __syncthreads();
  if (t == 0) {
    atomicAdd(&st[c], rs[0] + rs[1] + rs[2] + rs[3]);
    atomicAdd(&st[512 + c], rq[0] + rq[1] + rq[2] + rq[3]);
  }
}

// ---------------------------------------------------------------------------
// BN(train) + ReLU + pool4
// ---------------------------------------------------------------------------
__global__ __launch_bounds__(256) void bnrelu_pool_kernel(
    const float* __restrict__ Y, const float* __restrict__ st,
    const float* __restrict__ g, const float* __restrict__ bb,
    float* __restrict__ Z, int C, int H, int Lin, float invN,
    unsigned int total) {
  unsigned int idx = blockIdx.x * 256u + threadIdx.x;
  if (idx >= total) return;
  const unsigned int Lo = (unsigned int)(Lin >> 2);
  unsigned int lo = idx % Lo;
  unsigned int r1 = idx / Lo;
  unsigned int h = r1 % (unsigned int)H;
  unsigned int r2 = r1 / (unsigned int)H;
  unsigned int c = r2 % (unsigned int)C;
  unsigned int b = r2 / (unsigned int)C;
  float m = st[c] * invN;
  float v = st[512 + c] * invN - m * m;
  float sc = g[c] * rsqrtf(v + EPSBN);
  float bi = bb[c] - m * sc;
  const float* p = Y + (((size_t)b * C + c) * H + h) * Lin + 4u * lo;
  float a0 = p[0] * sc + bi, a1 = p[1] * sc + bi;
  float a2 = p[2] * sc + bi, a3 = p[3] * sc + bi;
  float r = fmaxf(fmaxf(a0, a1), fmaxf(a2, a3));
  Z[idx] = fmaxf(r, 0.f);
}

// ---------------------------------------------------------------------------
// BN(train) + ReLU, elementwise
// ---------------------------------------------------------------------------
__global__ __launch_bounds__(256) void bnrelu_kernel(
    const float* __restrict__ Y, const float* __restrict__ st,
    const float* __restrict__ g, const float* __restrict__ bb,
    float* __restrict__ A, int C, int HL, float invN, unsigned int total) {
  unsigned int idx = blockIdx.x * 256u + threadIdx.x;
  if (idx >= total) return;
  unsigned int c = (idx / (unsigned int)HL) % (unsigned int)C;
  float m = st[c] * invN;
  float v = st[512 + c] * invN - m * m;
  float sc = g[c] * rsqrtf(v + EPSBN);
  float bi = bb[c] - m * sc;
  A[idx] = fmaxf(fmaf(Y[idx], sc, bi), 0.f);
}

// ---------------------------------------------------------------------------
// Pack fp32 weights [Co][KTOT] -> per-s split bf16 packs with 2^-(s+i) folded:
// A[s][plane hi/lo][COPAD][KPAD]; i = (kk % (3*NK)) / 3.
// ---------------------------------------------------------------------------
__global__ __launch_bounds__(256) void pack_w2_kernel(
    const float* __restrict__ W, short* __restrict__ A, int Co, int KTOT,
    int KPAD, int COPAD, int NS, int nk3) {
  int idx = blockIdx.x * 256 + threadIdx.x;
  const int CK = COPAD * KPAD;
  if (idx >= NS * CK) return;
  int s = idx / CK;
  int rem = idx - s * CK;
  int co = rem / KPAD;
  int kk = rem - co * KPAD;
  float v = 0.f;
  if (co < Co && kk < KTOT) {
    int i = (kk % nk3) / 3;
    float scale = __uint_as_float((unsigned)(127 - (s + i)) << 23);
    v = W[co * KTOT + kk] * scale;
  }
  unsigned short hi = f2bf(v);
  unsigned short lo = f2bf(v - bf2f(hi));
  A[(size_t)s * 2 * CK + co * KPAD + kk] = (short)hi;
  A[(size_t)s * 2 * CK + CK + co * KPAD + kk] = (short)lo;
}

// ---------------------------------------------------------------------------
// gg_mfma2: split-precision bf16-MFMA GConvGG, staging-optimized.
// - Input X pre-activated fp32 (bn+relu applied upstream if needed);
//   2^-(s+i) scale folded into per-s A packs.
// - Table-driven gather (roT/shT per kk, built once per block).
// - Truncation hi/lo split (lo captures hi's residual; err ~2^-17).
// - XOR-swizzled B LDS layout: idx = l*72 + (kk&7) + 8*((kk>>3)^(l&7))
//   -> b16 writes and b128 MFMA reads both ~2-way (free).
// Block = 4 waves; wave = 16 co (m) x LT l (n, LT/16 tiles); K-chunks of 64.
// MFMA 16x16x32 bf16 layouts (verified in R8): A[m=lane&15][k=quad*8+j],
// B[k][n=lane&15], D col=lane&15 row=quad*4+reg.
// ---------------------------------------------------------------------------
template <int NKv, int LT>
__global__ __launch_bounds__(256) void gg_mfma2_kernel(
    const float* __restrict__ X, const short* __restrict__ Apk,
    float* __restrict__ Y, float* __restrict__ stOut, int Ci, int Co, int Hin,
    int L, int nL, int KTOT, int KPAD, int COPAD) {
  constexpr int T = LT / 16;       // l-tiles per wave
  constexpr int EPT = LT / 4;      // staged elements per thread per chunk
  constexpr int KSTR = 256 / LT;   // kk stride for staging

  const int bx = blockIdx.x;
  const int lc = bx % nL;
  const int cog = bx / nL;
  const int s = blockIdx.y;
  const int b = blockIdx.z;
  const int Hout = Hin - NKv + 1;
  const int l0 = lc * LT;
  const int tid = threadIdx.x;
  const int lane = tid & 63;
  const int quad = lane >> 4;
  const int m0 = lane & 15;
  const int wv = tid >> 6;
  const int coBase = cog * 64 + wv * 16;

  __shared__ __align__(16) short Bh[LT * 72];
  __shared__ __align__(16) short Bl[LT * 72];
  __shared__ int roT[512];
  __shared__ int shT[512];

  // ---- per-kk gather tables
  for (int kk = tid; kk < KPAD; kk += 256) {
    int ro = 0, sh = -(1 << 30);
    if (kk < KTOT) {
      int ci = kk / (3 * NKv);
      int rem = kk - ci * (3 * NKv);
      int i = rem / 3;
      int k = rem - 3 * i;
      ro = (ci * Hin + s + i) * L;
      sh = (k - 1) * (1 << (s + i));
    }
    roT[kk] = ro;
    shT[kk] = sh;
  }
  __syncthreads();

  f32x4 acc[T];
#pragma unroll
  for (int t = 0; t < T; ++t) acc[t] = (f32x4){0.f, 0.f, 0.f, 0.f};

  const short* ApkS = Apk + (size_t)s * 2 * COPAD * KPAD;
  const short* arowH = ApkS + (size_t)(coBase + m0) * KPAD;
  const short* arowL = arowH + (size_t)COPAD * KPAD;
  const float* Xb = X + (size_t)b * Ci * Hin * L;

  const int lB = tid & (LT - 1);
  const int kkW = tid / LT;
  const int nch = (KTOT + 63) >> 6;

  for (int c0 = 0; c0 < nch; ++c0) {
    // ---- stage B chunk: LT l x 64 kk (gather + trunc hi/lo split, swizzled)
#pragma unroll
    for (int r = 0; r < EPT; ++r) {
      const int kkL = kkW + KSTR * r;
      const int kk = (c0 << 6) + kkL;
      const int pos = l0 + lB + shT[kk];
      const int posc = min(max(pos, 0), L - 1);
      float x = Xb[roT[kk] + posc];
      unsigned u = __float_as_uint(x);
      if ((unsigned)pos >= (unsigned)L) u = 0u;
      unsigned hi = u >> 16;
      float lof = __uint_as_float(u) - __uint_as_float(u & 0xffff0000u);
      unsigned lo = __float_as_uint(lof) >> 16;
      const int widx = lB * 72 + (kkL & 7) + (((kkL >> 3) ^ (lB & 7)) << 3);
      Bh[widx] = (short)hi;
      Bl[widx] = (short)lo;
    }
    __syncthreads();
    // ---- MFMA: 2 K-steps of 32; per l-tile 3 split MFMAs
#pragma unroll
    for (int ks = 0; ks < 2; ++ks) {
      const int aoff = (c0 << 6) + ks * 32 + quad * 8;
      short8v ah = *(const short8v*)(arowH + aoff);
      short8v al = *(const short8v*)(arowL + aoff);
#pragma unroll
      for (int t = 0; t < T; ++t) {
        const int l = m0 + 16 * t;
        const int ridx = l * 72 + (((ks * 4 + quad) ^ (m0 & 7)) << 3);
        short8v bh = *(const short8v*)(Bh + ridx);
        short8v bl = *(const short8v*)(Bl + ridx);
        acc[t] = __builtin_amdgcn_mfma_f32_16x16x32_bf16(ah, bh, acc[t], 0, 0, 0);
        acc[t] = __builtin_amdgcn_mfma_f32_16x16x32_bf16(ah, bl, acc[t], 0, 0, 0);
        acc[t] = __builtin_amdgcn_mfma_f32_16x16x32_bf16(al, bh, acc[t], 0, 0, 0);
      }
    }
    __syncthreads();
  }

  // ---- epilogue: store + fused stats
#pragma unroll
  for (int reg = 0; reg < 4; ++reg) {
    const int co = coBase + quad * 4 + reg;
    if (co < Co) {
      float* yp = Y + (((size_t)b * Co + co) * Hout + s) * L + l0;
#pragma unroll
      for (int t = 0; t < T; ++t) yp[m0 + 16 * t] = acc[t][reg];
    }
  }
  if (stOut) {
#pragma unroll
    for (int reg = 0; reg < 4; ++reg) {
      float s1 = 0.f, s2 = 0.f;
#pragma unroll
      for (int t = 0; t < T; ++t) {
        s1 += acc[t][reg];
        s2 += acc[t][reg] * acc[t][reg];
      }
#pragma unroll
      for (int off = 1; off < 16; off <<= 1) {
        s1 += __shfl_xor(s1, off);
        s2 += __shfl_xor(s2, off);
      }
      const int co = coBase + quad * 4 + reg;
      if (m0 == 0 && co < Co) {
        atomicAdd(&stOut[co], s1);
        atomicAdd(&stOut[512 + co], s2);
      }
    }
  }
}

// ---------------------------------------------------------------------------
// gg_tail: no-LDS GConvGG for small stages (input pre-activated)
// ---------------------------------------------------------------------------
template <int NK, int L, int COSUB>
__global__ __launch_bounds__(256) void gg_tail_kernel(
    const float* __restrict__ X, const float* __restrict__ W,
    float* __restrict__ Y, float* __restrict__ stOut, int Ci, int Co,
    int Hin) {
  const int l = threadIdx.x % L;
  const int cs = threadIdx.x / L;
  const int co = blockIdx.x * COSUB + cs;
  const int s = blockIdx.y;
  const int b = blockIdx.z;
  const int Hout = Hin - NK + 1;

  float acc[NK];
#pragma unroll
  for (int i = 0; i < NK; ++i) acc[i] = 0.f;

  const float* wbase = W + (size_t)co * Ci * NK * 3;
  const float* xbase = X + ((size_t)b * Ci * Hin + s) * L;

  for (int ci = 0; ci < Ci; ++ci) {
    const float* wp = wbase + ci * (NK * 3);
    const float* xr = xbase + ci * (Hin * L);
#pragma unroll
    for (int i = 0; i < NK; ++i) {
      const int d = 1 << (s + i);
      const float* row = xr + i * L;
      float xm = (l >= d) ? row[l - d] : 0.f;
      float xc = row[l];
      float xp = (l + d < L) ? row[l + d] : 0.f;
      acc[i] = fmaf(wp[3 * i], xm,
                    fmaf(wp[3 * i + 1], xc, fmaf(wp[3 * i + 2], xp, acc[i])));
    }
  }
  float out = 0.f;
#pragma unroll
  for (int i = 0; i < NK; ++i) {
    float invd = __uint_as_float((unsigned)(127 - (s + i)) << 23);
    out = fmaf(acc[i], invd, out);
  }
  Y[(((size_t)b * Co + co) * Hout + s) * L + l] = out;

  float s1 = out, s2 = out * out;
  constexpr int RED = (L < 64) ? L : 64;
#pragma unroll
  for (int off = RED / 2; off > 0; off >>= 1) {
    s1 += __shfl_xor(s1, off);
    s2 += __shfl_xor(s2, off);
  }
  if ((threadIdx.x & (RED - 1)) == 0) {
    atomicAdd(&stOut[co], s1);
    atomicAdd(&stOut[512 + co], s2);
  }
}

// ---------------------------------------------------------------------------
// Final: bn10+relu, mean over L, classifier
// ---------------------------------------------------------------------------
__global__ __launch_bounds__(256) void final_kernel(
    const float* __restrict__ Y, const float* __restrict__ st,
    const float* __restrict__ g, const float* __restrict__ bb,
    const float* __restrict__ w11, float* __restrict__ out) {
  const int b = blockIdx.x;
  const int tid = threadIdx.x;
  __shared__ float tch[408];
  for (int c = tid; c < 408; c += 256) {
    float m = st[c] * (1.f / 256.f);
    float v = st[512 + c] * (1.f / 256.f) - m * m;
    float sc = g[c] * rsqrtf(v + EPSBN);
    float bi = bb[c] - m * sc;
    const float* p = Y + ((size_t)b * 408 + c) * 32;
    float ssum = 0.f;
#pragma unroll
    for (int l = 0; l < 32; ++l) ssum += fmaxf(p[l] * sc + bi, 0.f);
    tch[c] = ssum * (1.f / 32.f);
  }
  __syncthreads();
  if (tid < 10) {
    float ssum = 0.f;
    for (int c = 0; c < 408; ++c) ssum += w11[tid * 408 + c] * tch[c];
    out[b * 10 + tid] = ssum;
  }
}

// ---------------------------------------------------------------------------
extern "C" void kernel_launch(void* const* d_in, const int* in_sizes, int n_in,
                              void* d_out, int out_size, void* d_ws,
                              size_t ws_size, hipStream_t stream) {
  const float* x = (const float*)d_in[0];
  const float* w1 = (const float*)d_in[1];
  const float* w2 = (const float*)d_in[2];
  const float* w3 = (const float*)d_in[3];
  const float* w4 = (const float*)d_in[4];
  const float* w5 = (const float*)d_in[5];
  const float* w6 = (const float*)d_in[6];
  const float* w7 = (const float*)d_in[7];
  const float* w8 = (const float*)d_in[8];
  const float* w9 = (const float*)d_in[9];
  const float* w10 = (const float*)d_in[10];
  const float* w11 = (const float*)d_in[11];
  const float* gg[11];
  const float* bbv[11];
  for (int i = 1; i <= 10; ++i) {
    gg[i] = (const float*)d_in[12 + 2 * (i - 1)];
    bbv[i] = (const float*)d_in[12 + 2 * (i - 1) + 1];
  }

  float* ws = (float*)d_ws;
  const size_t AR0 = 0;
  const size_t AR1 = 30081024;
  const size_t STATS = 37601280;
  float* y1 = ws + AR0;
  float* xpad = ws + AR1;
  float* z1 = ws + AR1;
  float* y2 = ws + AR0;
  float* y3 = ws + AR0 + 5849088;
  float* a3act = ws + AR1;              // 5849088 fl (z1 dead after gg2)
  float* z3 = ws + AR1;                 // 1462272 fl (a3act dead after gg3)
  float* y4 = ws + AR0;
  float* y5 = ws + AR0 + 2088960;
  float* a5act = ws + AR1 + 1500000;    // 2088960 fl (z3 dead after gg4)
  float* z5 = ws + AR1;
  float* a6 = ws + AR1 + 522240;
  float* a7 = ws + AR1 + 1148928;
  float* z8 = ws + AR1;
  float* a9 = ws + AR1 + 1775616;
  float* y6 = ws + AR0;
  float* y7 = ws + AR0 + 626688;
  float* y8 = ws + AR0 + 1253376;
  float* y9 = ws + AR0;
  float* y10 = ws + AR0 + 104448;
  // per-s split-bf16 weight packs, above live AR0 tensors (y3 ends 11698176)
  short* apk2 = (short*)(ws + 12000000);          // 7*2*64*512  = 458752 sh
  short* apk3 = apk2 + 7 * 2 * 64 * 512;          // 7*2*64*192  = 172032 sh
  short* apk4 = apk3 + 7 * 2 * 64 * 192;          // 5*2*128*512 = 655360 sh
  short* apk5 = apk4 + 5 * 2 * 128 * 512;         // 5*2*128*320 = 409600 sh
  float* st[11];
  for (int i = 1; i <= 10; ++i) st[i] = ws + STATS + (size_t)(i - 1) * 1024;

  hipMemsetAsync((void*)(ws + STATS), 0, 10 * 1024 * sizeof(float), stream);

  // ---- pad + lift (stats1 fused)
  pad_x_kernel<<<(8 * PROW + 255) / 256, 256, 0, stream>>>(x, xpad);
  {
    dim3 g(8, 51, 8);
    lift_pool2_kernel<0><<<g, 256, 0, stream>>>(xpad, w1, y1, st[1]);
    lift_pool2_kernel<1><<<g, 256, 0, stream>>>(xpad, w1, y1, st[1]);
    lift_pool2_kernel<2><<<g, 256, 0, stream>>>(xpad, w1, y1, st[1]);
    lift_pool2_kernel<3><<<g, 256, 0, stream>>>(xpad, w1, y1, st[1]);
    lift_pool2_kernel<4><<<g, 256, 0, stream>>>(xpad, w1, y1, st[1]);
    lift_pool2_kernel<5><<<g, 256, 0, stream>>>(xpad, w1, y1, st[1]);
    lift_pool2_kernel<6><<<g, 256, 0, stream>>>(xpad, w1, y1, st[1]);
    lift_pool2_kernel<7><<<g, 256, 0, stream>>>(xpad, w1, y1, st[1]);
    lift_pool2_kernel<8><<<g, 256, 0, stream>>>(xpad, w1, y1, st[1]);
  }
  {
    unsigned int tot = 8u * 51 * 9 * 2048;
    bnrelu_pool_kernel<<<(tot + 255) / 256, 256, 0, stream>>>(
        y1, st[1], gg[1], bbv[1], z1, 51, 9, 8192, 1.f / 589824.f, tot);
  }
  // ---- per-s weight packs (scale 2^-(s+i) folded)
  pack_w2_kernel<<<(7 * 64 * 512 + 255) / 256, 256, 0, stream>>>(
      w2, apk2, 51, 459, 512, 64, 7, 9);
  pack_w2_kernel<<<(7 * 64 * 192 + 255) / 256, 256, 0, stream>>>(
      w3, apk3, 51, 153, 192, 64, 7, 3);
  pack_w2_kernel<<<(5 * 128 * 512 + 255) / 256, 256, 0, stream>>>(
      w4, apk4, 102, 459, 512, 128, 5, 9);
  pack_w2_kernel<<<(5 * 128 * 320 + 255) / 256, 256, 0, stream>>>(
      w5, apk5, 102, 306, 320, 128, 5, 3);
  // ---- gg2: 51->51, H 9->7, L=2048 (MFMA, stats fused)
  gg_mfma2_kernel<3, 64><<<dim3(32, 7, 8), 256, 0, stream>>>(
      z1, apk2, y2, st[2], 51, 51, 9, 2048, 32, 459, 512, 64);
  // ---- activate y2 -> a3act (bn2+relu)
  {
    unsigned int tot = 8u * 51 * 7 * 2048;
    bnrelu_kernel<<<(tot + 255) / 256, 256, 0, stream>>>(
        y2, st[2], gg[2], bbv[2], a3act, 51, 7 * 2048, 1.f / 114688.f, tot);
  }
  // ---- gg3: 51->51, H7, L=2048
  gg_mfma2_kernel<1, 64><<<dim3(32, 7, 8), 256, 0, stream>>>(
      a3act, apk3, y3, st[3], 51, 51, 7, 2048, 32, 153, 192, 64);
  {
    unsigned int tot = 8u * 51 * 7 * 512;
    bnrelu_pool_kernel<<<(tot + 255) / 256, 256, 0, stream>>>(
        y3, st[3], gg[3], bbv[3], z3, 51, 7, 2048, 1.f / 114688.f, tot);
  }
  // ---- gg4: 51->102, H 7->5, L=512 (2 co-groups)
  gg_mfma2_kernel<3, 32><<<dim3(32, 5, 8), 256, 0, stream>>>(
      z3, apk4, y4, st[4], 51, 102, 7, 512, 16, 459, 512, 128);
  // ---- activate y4 -> a5act (bn4+relu)
  {
    unsigned int tot = 8u * 102 * 5 * 512;
    bnrelu_kernel<<<(tot + 255) / 256, 256, 0, stream>>>(
        y4, st[4], gg[4], bbv[4], a5act, 102, 5 * 512, 1.f / 20480.f, tot);
  }
  // ---- gg5: 102->102, H5, L=512
  gg_mfma2_kernel<1, 32><<<dim3(32, 5, 8), 256, 0, stream>>>(
      a5act, apk5, y5, st[5], 102, 102, 5, 512, 16, 306, 320, 128);
  {
    unsigned int tot = 8u * 102 * 5 * 128;
    bnrelu_pool_kernel<<<(tot + 255) / 256, 256, 0, stream>>>(
        y5, st[5], gg[5], bbv[5], z5, 102, 5, 512, 1.f / 20480.f, tot);
  }
  // ---- gg6: 102->204, H 5->3, L=128
  gg_tail_kernel<3, 128, 2><<<dim3(102, 3, 8), 256, 0, stream>>>(
      z5, w6, y6, st[6], 102, 204, 5);
  {
    unsigned int tot = 8u * 204 * 3 * 128;
    bnrelu_kernel<<<(tot + 255) / 256, 256, 0, stream>>>(
        y6, st[6], gg[6], bbv[6], a6, 204, 3 * 128, 1.f / 3072.f, tot);
  }
  // ---- gg7: 204->204, H3, L=128
  gg_tail_kernel<1, 128, 2><<<dim3(102, 3, 8), 256, 0, stream>>>(
      a6, w7, y7, st[7], 204, 204, 3);
  {
    unsigned int tot = 8u * 204 * 3 * 128;
    bnrelu_kernel<<<(tot + 255) / 256, 256, 0, stream>>>(
        y7, st[7], gg[7], bbv[7], a7, 204, 3 * 128, 1.f / 3072.f, tot);
  }
  // ---- gg8: 204->204, H3, L=128
  gg_tail_kernel<1, 128, 2><<<dim3(102, 3, 8), 256, 0, stream>>>(
      a7, w8, y8, st[8], 204, 204, 3);
  {
    unsigned int tot = 8u * 204 * 3 * 32;
    bnrelu_pool_kernel<<<(tot + 255) / 256, 256, 0, stream>>>(
        y8, st[8], gg[8], bbv[8], z8, 204, 3, 128, 1.f / 3072.f, tot);
  }
  // ---- gg9: 204->408, H 3->1, L=32
  gg_tail_kernel<3, 32, 8><<<dim3(51, 1, 8), 256, 0, stream>>>(
      z8, w9, y9, st[9], 204, 408, 3);
  {
    unsigned int tot = 8u * 408 * 32;
    bnrelu_kernel<<<(tot + 255) / 256, 256, 0, stream>>>(
        y9, st[9], gg[9], bbv[9], a9, 408, 32, 1.f / 256.f, tot);
  }
  // ---- gg10: 408->408, H1, L=32
  gg_tail_kernel<1, 32, 8><<<dim3(51, 1, 8), 256, 0, stream>>>(
      a9, w10, y10, st[10], 408, 408, 1);
  // ---- final
  final_kernel<<<dim3(8), 256, 0, stream>>>(y10, st[10], gg[10], bbv[10], w11,
                                            (float*)d_out);
}

// Round 10
// 1875.706 us; speedup vs baseline: 1.1903x; 1.0745x over previous
//
#include <hip/hip_runtime.h>
#include <hip/hip_bf16.h>

#define EPSBN 2e-5f

typedef __attribute__((ext_vector_type(8))) short short8v;
typedef __attribute__((ext_vector_type(4))) float f32x4;

__device__ inline unsigned short f2bf(float f) {
  unsigned u = __float_as_uint(f);
  unsigned r = (u + 0x7FFFu + ((u >> 16) & 1u)) >> 16;
  return (unsigned short)r;
}
__device__ inline float bf2f(unsigned short h) {
  return __uint_as_float(((unsigned)h) << 16);
}
// packed RNE f32x2 -> bf16x2 dword
__device__ inline unsigned pkbf(float a, float b) {
  __hip_bfloat162 q = __float22bfloat162_rn(make_float2(a, b));
  return *reinterpret_cast<unsigned*>(&q);
}

// ---------------------------------------------------------------------------
// Padded x staging
// ---------------------------------------------------------------------------
constexpr int XPADL = 9984;
constexpr int XPADR = 14336;
constexpr int PROW = XPADL + 32768 + XPADR;  // 57088

__global__ __launch_bounds__(256) void pad_x_kernel(const float* __restrict__ x,
                                                    float* __restrict__ xp) {
  int i = blockIdx.x * 256 + threadIdx.x;
  if (i >= 8 * PROW) return;
  int b = i / PROW;
  int pos = i - b * PROW - XPADL;
  xp[i] = (pos >= 0 && pos < 32768) ? x[b * 32768 + pos] : 0.f;
}

// ---------------------------------------------------------------------------
// Lift conv K=79 (dilation 2^S, scale 1/2^S) + pool4 + BN-stats, templated S.
// ---------------------------------------------------------------------------
template <int S>
__global__ __launch_bounds__(256) void lift_pool2_kernel(
    const float* __restrict__ xp, const float* __restrict__ w1,
    float* __restrict__ y1, float* __restrict__ st) {
  constexpr int d = 1 << S;
  constexpr float inv = 1.f / (float)d;
  const int tile = blockIdx.x;
  const int c = blockIdx.y;
  const int b = blockIdx.z;
  const int l0 = tile * 4096;
  const int t = threadIdx.x;
  const int q = t & (d - 1);
  const int j = t >> S;
  const int base = l0 + q + ((j * 16) << S);
  const float* xrow = xp + b * PROW + XPADL;
  const float* wr = w1 + c * 79;

  float acc[16], win[16];
#pragma unroll
  for (int r = 0; r < 16; ++r) acc[r] = 0.f;
  int idx = base - 39 * d;
#pragma unroll
  for (int i = 0; i < 16; ++i) {
    win[i] = xrow[idx];
    idx += d;
  }
#pragma unroll
  for (int ko = 0; ko < 5; ++ko) {
#pragma unroll
    for (int kj = 0; kj < 16; ++kj) {
      const int k = ko * 16 + kj;
      const float wk = (k < 79) ? wr[k] : 0.f;
#pragma unroll
      for (int r = 0; r < 16; ++r)
        acc[r] = fmaf(wk, win[(kj + r) & 15], acc[r]);
      win[kj] = xrow[idx];
      idx += d;
    }
  }

  float ssum = 0.f, ssq = 0.f;
  float* yrow = y1 + (((size_t)b * 51 + c) * 9 + S) * 8192 + (l0 >> 2);
  if constexpr (S == 0) {
#pragma unroll
    for (int m = 0; m < 4; ++m) {
      float v = fmaxf(fmaxf(acc[4 * m], acc[4 * m + 1]),
                      fmaxf(acc[4 * m + 2], acc[4 * m + 3]));
      yrow[4 * t + m] = v;
      ssum += v;
      ssq += v * v;
    }
  } else if constexpr (S == 1) {
#pragma unroll
    for (int m = 0; m < 8; ++m) {
      float u = fmaxf(acc[2 * m], acc[2 * m + 1]);
      u = fmaxf(u, __shfl_xor(u, 1));
      if ((t & 1) == 0) {
        float v = u * inv;
        yrow[8 * j + m] = v;
        ssum += v;
        ssq += v * v;
      }
    }
  } else {
#pragma unroll
    for (int r = 0; r < 16; ++r) {
      float u = fmaxf(acc[r], __shfl_xor(acc[r], 1));
      u = fmaxf(u, __shfl_xor(u, 2));
      if ((t & 3) == 0) {
        float v = u * inv;
        yrow[(q >> 2) + ((j * 16 + r) << (S - 2))] = v;
        ssum += v;
        ssq += v * v;
      }
    }
  }
#pragma unroll
  for (int off = 32; off > 0; off >>= 1) {
    ssum += __shfl_down(ssum, off);
    ssq += __shfl_down(ssq, off);
  }
  __shared__ float rs[4], rq[4];
  const int wid = t >> 6;
  if ((t & 63) == 0) {
    rs[wid] = ssum;
    rq[wid] = ssq;
  }
  __syncthreads();
  if (t == 0) {
    atomicAdd(&st[c], rs[0] + rs[1] + rs[2] + rs[3]);
    atomicAdd(&st[512 + c], rq[0] + rq[1] + rq[2] + rq[3]);
  }
}

// ---------------------------------------------------------------------------
// BN(train) + ReLU + pool4
// ---------------------------------------------------------------------------
__global__ __launch_bounds__(256) void bnrelu_pool_kernel(
    const float* __restrict__ Y, const float* __restrict__ st,
    const float* __restrict__ g, const float* __restrict__ bb,
    float* __restrict__ Z, int C, int H, int Lin, float invN,
    unsigned int total) {
  unsigned int idx = blockIdx.x * 256u + threadIdx.x;
  if (idx >= total) return;
  const unsigned int Lo = (unsigned int)(Lin >> 2);
  unsigned int lo = idx % Lo;
  unsigned int r1 = idx / Lo;
  unsigned int h = r1 % (unsigned int)H;
  unsigned int r2 = r1 / (unsigned int)H;
  unsigned int c = r2 % (unsigned int)C;
  unsigned int b = r2 / (unsigned int)C;
  float m = st[c] * invN;
  float v = st[512 + c] * invN - m * m;
  float sc = g[c] * rsqrtf(v + EPSBN);
  float bi = bb[c] - m * sc;
  const float* p = Y + (((size_t)b * C + c) * H + h) * Lin + 4u * lo;
  float a0 = p[0] * sc + bi, a1 = p[1] * sc + bi;
  float a2 = p[2] * sc + bi, a3 = p[3] * sc + bi;
  float r = fmaxf(fmaxf(a0, a1), fmaxf(a2, a3));
  Z[idx] = fmaxf(r, 0.f);
}

// ---------------------------------------------------------------------------
// BN(train) + ReLU, elementwise
// ---------------------------------------------------------------------------
__global__ __launch_bounds__(256) void bnrelu_kernel(
    const float* __restrict__ Y, const float* __restrict__ st,
    const float* __restrict__ g, const float* __restrict__ bb,
    float* __restrict__ A, int C, int HL, float invN, unsigned int total) {
  unsigned int idx = blockIdx.x * 256u + threadIdx.x;
  if (idx >= total) return;
  unsigned int c = (idx / (unsigned int)HL) % (unsigned int)C;
  float m = st[c] * invN;
  float v = st[512 + c] * invN - m * m;
  float sc = g[c] * rsqrtf(v + EPSBN);
  float bi = bb[c] - m * sc;
  A[idx] = fmaxf(fmaf(Y[idx], sc, bi), 0.f);
}

// ---------------------------------------------------------------------------
// Pack fp32 weights [Co][KTOT] -> per-s split bf16 packs with 2^-(s+i) folded:
// A[s][plane hi/lo][COPAD][KPAD]; i = (kk % (3*NK)) / 3.
// ---------------------------------------------------------------------------
__global__ __launch_bounds__(256) void pack_w2_kernel(
    const float* __restrict__ W, short* __restrict__ A, int Co, int KTOT,
    int KPAD, int COPAD, int NS, int nk3) {
  int idx = blockIdx.x * 256 + threadIdx.x;
  const int CK = COPAD * KPAD;
  if (idx >= NS * CK) return;
  int s = idx / CK;
  int rem = idx - s * CK;
  int co = rem / KPAD;
  int kk = rem - co * KPAD;
  float v = 0.f;
  if (co < Co && kk < KTOT) {
    int i = (kk % nk3) / 3;
    float scale = __uint_as_float((unsigned)(127 - (s + i)) << 23);
    v = W[co * KTOT + kk] * scale;
  }
  unsigned short hi = f2bf(v);
  unsigned short lo = f2bf(v - bf2f(hi));
  A[(size_t)s * 2 * CK + co * KPAD + kk] = (short)hi;
  A[(size_t)s * 2 * CK + CK + co * KPAD + kk] = (short)lo;
}

// ---------------------------------------------------------------------------
// gg_mfma3: bf16-MFMA GConvGG, A-split (hi/lo weights) x single-RNE-bf16 B.
// Per K-step 2 MFMAs: Ah*B + Al*B (weight quantization ~2^-17; B ~2^-9 —
// half the R7 error). B staged in plain [l][72] LDS (no swizzle):
// staging thread = (l, kk-oct): 8 gathered loads -> 1 ds_write_b128; MFMA
// fragment read = 1 aligned ds_read_b128. At row pitch 144B both ops put
// 64 lanes x 16B uniformly 8-deep over all 32 banks (bandwidth-minimal).
// Gather tables (row offset / dilated shift per kk) built once per block;
// table reads are wave-uniform. MFMA 16x16x32 bf16 layouts (R8-verified).
// ---------------------------------------------------------------------------
template <int NKv, int LT>
__global__ __launch_bounds__(256) void gg_mfma3_kernel(
    const float* __restrict__ X, const short* __restrict__ Apk,
    float* __restrict__ Y, float* __restrict__ stOut, int Ci, int Co, int Hin,
    int L, int nL, int KTOT, int KPAD, int COPAD) {
  constexpr int T = LT / 16;      // l-tiles per wave
  constexpr int KO = 256 / LT;    // kk-octs covered per staging pass
  constexpr int RIT = 8 / KO;     // staging iterations (8 octs per chunk)

  const int bx = blockIdx.x;
  const int lc = bx % nL;
  const int cog = bx / nL;
  const int s = blockIdx.y;
  const int b = blockIdx.z;
  const int Hout = Hin - NKv + 1;
  const int l0 = lc * LT;
  const int tid = threadIdx.x;
  const int lane = tid & 63;
  const int quad = lane >> 4;
  const int m0 = lane & 15;
  const int wv = tid >> 6;
  const int coBase = cog * 64 + wv * 16;

  __shared__ __align__(16) short Bh[LT * 72];
  __shared__ int roT[512];
  __shared__ int shT[512];

  // ---- per-kk gather tables
  for (int kk = tid; kk < KPAD; kk += 256) {
    int ro = 0, sh = -(1 << 30);
    if (kk < KTOT) {
      int ci = kk / (3 * NKv);
      int rem = kk - ci * (3 * NKv);
      int i = rem / 3;
      int k = rem - 3 * i;
      ro = (ci * Hin + s + i) * L;
      sh = (k - 1) * (1 << (s + i));
    }
    roT[kk] = ro;
    shT[kk] = sh;
  }
  __syncthreads();

  f32x4 acc[T];
#pragma unroll
  for (int t = 0; t < T; ++t) acc[t] = (f32x4){0.f, 0.f, 0.f, 0.f};

  const short* ApkS = Apk + (size_t)s * 2 * COPAD * KPAD;
  const short* arowH = ApkS + (size_t)(coBase + m0) * KPAD;
  const short* arowL = arowH + (size_t)COPAD * KPAD;
  const float* Xb = X + (size_t)b * Ci * Hin * L;

  const int lB = tid & (LT - 1);
  const int oc0 = tid / LT;  // 0..KO-1
  const int nch = (KTOT + 63) >> 6;

  for (int c0 = 0; c0 < nch; ++c0) {
    // ---- stage B chunk: LT l x 64 kk; thread = (l, kk-oct): 8 loads ->
    // one b128 write (plain layout, uniform bank load)
#pragma unroll
    for (int r = 0; r < RIT; ++r) {
      const int oct = oc0 + KO * r;
      const int kkb = (c0 << 6) + oct * 8;
      float v[8];
#pragma unroll
      for (int j = 0; j < 8; ++j) {
        const int kk = kkb + j;
        const int pos = l0 + lB + shT[kk];
        const int posc = min(max(pos, 0), L - 1);
        float x = Xb[roT[kk] + posc];
        v[j] = ((unsigned)pos < (unsigned)L) ? x : 0.f;
      }
      uint4 pk;
      pk.x = pkbf(v[0], v[1]);
      pk.y = pkbf(v[2], v[3]);
      pk.z = pkbf(v[4], v[5]);
      pk.w = pkbf(v[6], v[7]);
      *(uint4*)(Bh + lB * 72 + oct * 8) = pk;
    }
    __syncthreads();
    // ---- MFMA: 2 K-steps of 32; per l-tile: 1 b128 read + 2 split MFMAs
#pragma unroll
    for (int ks = 0; ks < 2; ++ks) {
      const int aoff = (c0 << 6) + ks * 32 + quad * 8;
      short8v ah = *(const short8v*)(arowH + aoff);
      short8v al = *(const short8v*)(arowL + aoff);
#pragma unroll
      for (int t = 0; t < T; ++t) {
        const int l = m0 + 16 * t;
        short8v bf = *(const short8v*)(Bh + l * 72 + ks * 32 + quad * 8);
        acc[t] = __builtin_amdgcn_mfma_f32_16x16x32_bf16(ah, bf, acc[t], 0, 0, 0);
        acc[t] = __builtin_amdgcn_mfma_f32_16x16x32_bf16(al, bf, acc[t], 0, 0, 0);
      }
    }
    __syncthreads();
  }

  // ---- epilogue: store + fused stats
#pragma unroll
  for (int reg = 0; reg < 4; ++reg) {
    const int co = coBase + quad * 4 + reg;
    if (co < Co) {
      float* yp = Y + (((size_t)b * Co + co) * Hout + s) * L + l0;
#pragma unroll
      for (int t = 0; t < T; ++t) yp[m0 + 16 * t] = acc[t][reg];
    }
  }
  if (stOut) {
#pragma unroll
    for (int reg = 0; reg < 4; ++reg) {
      float s1 = 0.f, s2 = 0.f;
#pragma unroll
      for (int t = 0; t < T; ++t) {
        s1 += acc[t][reg];
        s2 += acc[t][reg] * acc[t][reg];
      }
#pragma unroll
      for (int off = 1; off < 16; off <<= 1) {
        s1 += __shfl_xor(s1, off);
        s2 += __shfl_xor(s2, off);
      }
      const int co = coBase + quad * 4 + reg;
      if (m0 == 0 && co < Co) {
        atomicAdd(&stOut[co], s1);
        atomicAdd(&stOut[512 + co], s2);
      }
    }
  }
}

// ---------------------------------------------------------------------------
// gg_tail: no-LDS GConvGG for small stages (input pre-activated)
// ---------------------------------------------------------------------------
template <int NK, int L, int COSUB>
__global__ __launch_bounds__(256) void gg_tail_kernel(
    const float* __restrict__ X, const float* __restrict__ W,
    float* __restrict__ Y, float* __restrict__ stOut, int Ci, int Co,
    int Hin) {
  const int l = threadIdx.x % L;
  const int cs = threadIdx.x / L;
  const int co = blockIdx.x * COSUB + cs;
  const int s = blockIdx.y;
  const int b = blockIdx.z;
  const int Hout = Hin - NK + 1;

  float acc[NK];
#pragma unroll
  for (int i = 0; i < NK; ++i) acc[i] = 0.f;

  const float* wbase = W + (size_t)co * Ci * NK * 3;
  const float* xbase = X + ((size_t)b * Ci * Hin + s) * L;

  for (int ci = 0; ci < Ci; ++ci) {
    const float* wp = wbase + ci * (NK * 3);
    const float* xr = xbase + ci * (Hin * L);
#pragma unroll
    for (int i = 0; i < NK; ++i) {
      const int d = 1 << (s + i);
      const float* row = xr + i * L;
      float xm = (l >= d) ? row[l - d] : 0.f;
      float xc = row[l];
      float xp = (l + d < L) ? row[l + d] : 0.f;
      acc[i] = fmaf(wp[3 * i], xm,
                    fmaf(wp[3 * i + 1], xc, fmaf(wp[3 * i + 2], xp, acc[i])));
    }
  }
  float out = 0.f;
#pragma unroll
  for (int i = 0; i < NK; ++i) {
    float invd = __uint_as_float((unsigned)(127 - (s + i)) << 23);
    out = fmaf(acc[i], invd, out);
  }
  Y[(((size_t)b * Co + co) * Hout + s) * L + l] = out;

  float s1 = out, s2 = out * out;
  constexpr int RED = (L < 64) ? L : 64;
#pragma unroll
  for (int off = RED / 2; off > 0; off >>= 1) {
    s1 += __shfl_xor(s1, off);
    s2 += __shfl_xor(s2, off);
  }
  if ((threadIdx.x & (RED - 1)) == 0) {
    atomicAdd(&stOut[co], s1);
    atomicAdd(&stOut[512 + co], s2);
  }
}

// ---------------------------------------------------------------------------
// Final: bn10+relu, mean over L, classifier
// ---------------------------------------------------------------------------
__global__ __launch_bounds__(256) void final_kernel(
    const float* __restrict__ Y, const float* __restrict__ st,
    const float* __restrict__ g, const float* __restrict__ bb,
    const float* __restrict__ w11, float* __restrict__ out) {
  const int b = blockIdx.x;
  const int tid = threadIdx.x;
  __shared__ float tch[408];
  for (int c = tid; c < 408; c += 256) {
    float m = st[c] * (1.f / 256.f);
    float v = st[512 + c] * (1.f / 256.f) - m * m;
    float sc = g[c] * rsqrtf(v + EPSBN);
    float bi = bb[c] - m * sc;
    const float* p = Y + ((size_t)b * 408 + c) * 32;
    float ssum = 0.f;
#pragma unroll
    for (int l = 0; l < 32; ++l) ssum += fmaxf(p[l] * sc + bi, 0.f);
    tch[c] = ssum * (1.f / 32.f);
  }
  __syncthreads();
  if (tid < 10) {
    float ssum = 0.f;
    for (int c = 0; c < 408; ++c) ssum += w11[tid * 408 + c] * tch[c];
    out[b * 10 + tid] = ssum;
  }
}

// ---------------------------------------------------------------------------
extern "C" void kernel_launch(void* const* d_in, const int* in_sizes, int n_in,
                              void* d_out, int out_size, void* d_ws,
                              size_t ws_size, hipStream_t stream) {
  const float* x = (const float*)d_in[0];
  const float* w1 = (const float*)d_in[1];
  const float* w2 = (const float*)d_in[2];
  const float* w3 = (const float*)d_in[3];
  const float* w4 = (const float*)d_in[4];
  const float* w5 = (const float*)d_in[5];
  const float* w6 = (const float*)d_in[6];
  const float* w7 = (const float*)d_in[7];
  const float* w8 = (const float*)d_in[8];
  const float* w9 = (const float*)d_in[9];
  const float* w10 = (const float*)d_in[10];
  const float* w11 = (const float*)d_in[11];
  const float* gg[11];
  const float* bbv[11];
  for (int i = 1; i <= 10; ++i) {
    gg[i] = (const float*)d_in[12 + 2 * (i - 1)];
    bbv[i] = (const float*)d_in[12 + 2 * (i - 1) + 1];
  }

  float* ws = (float*)d_ws;
  const size_t AR0 = 0;
  const size_t AR1 = 30081024;
  const size_t STATS = 37601280;
  float* y1 = ws + AR0;
  float* xpad = ws + AR1;
  float* z1 = ws + AR1;
  float* y2 = ws + AR0;
  float* y3 = ws + AR0 + 5849088;
  float* a3act = ws + AR1;              // z1 dead after gg2
  float* z3 = ws + AR1;
  float* y4 = ws + AR0;
  float* y5 = ws + AR0 + 2088960;
  float* a5act = ws + AR1 + 1500000;
  float* z5 = ws + AR1;
  float* a6 = ws + AR1 + 522240;
  float* a7 = ws + AR1 + 1148928;
  float* z8 = ws + AR1;
  float* a9 = ws + AR1 + 1775616;
  float* y6 = ws + AR0;
  float* y7 = ws + AR0 + 626688;
  float* y8 = ws + AR0 + 1253376;
  float* y9 = ws + AR0;
  float* y10 = ws + AR0 + 104448;
  short* apk2 = (short*)(ws + 12000000);  // 7*2*64*512
  short* apk3 = apk2 + 7 * 2 * 64 * 512;  // 7*2*64*192
  short* apk4 = apk3 + 7 * 2 * 64 * 192;  // 5*2*128*512
  short* apk5 = apk4 + 5 * 2 * 128 * 512; // 5*2*128*320
  float* st[11];
  for (int i = 1; i <= 10; ++i) st[i] = ws + STATS + (size_t)(i - 1) * 1024;

  hipMemsetAsync((void*)(ws + STATS), 0, 10 * 1024 * sizeof(float), stream);

  // ---- pad + lift (stats1 fused)
  pad_x_kernel<<<(8 * PROW + 255) / 256, 256, 0, stream>>>(x, xpad);
  {
    dim3 g(8, 51, 8);
    lift_pool2_kernel<0><<<g, 256, 0, stream>>>(xpad, w1, y1, st[1]);
    lift_pool2_kernel<1><<<g, 256, 0, stream>>>(xpad, w1, y1, st[1]);
    lift_pool2_kernel<2><<<g, 256, 0, stream>>>(xpad, w1, y1, st[1]);
    lift_pool2_kernel<3><<<g, 256, 0, stream>>>(xpad, w1, y1, st[1]);
    lift_pool2_kernel<4><<<g, 256, 0, stream>>>(xpad, w1, y1, st[1]);
    lift_pool2_kernel<5><<<g, 256, 0, stream>>>(xpad, w1, y1, st[1]);
    lift_pool2_kernel<6><<<g, 256, 0, stream>>>(xpad, w1, y1, st[1]);
    lift_pool2_kernel<7><<<g, 256, 0, stream>>>(xpad, w1, y1, st[1]);
    lift_pool2_kernel<8><<<g, 256, 0, stream>>>(xpad, w1, y1, st[1]);
  }
  {
    unsigned int tot = 8u * 51 * 9 * 2048;
    bnrelu_pool_kernel<<<(tot + 255) / 256, 256, 0, stream>>>(
        y1, st[1], gg[1], bbv[1], z1, 51, 9, 8192, 1.f / 589824.f, tot);
  }
  // ---- per-s weight packs (scale folded)
  pack_w2_kernel<<<(7 * 64 * 512 + 255) / 256, 256, 0, stream>>>(
      w2, apk2, 51, 459, 512, 64, 7, 9);
  pack_w2_kernel<<<(7 * 64 * 192 + 255) / 256, 256, 0, stream>>>(
      w3, apk3, 51, 153, 192, 64, 7, 3);
  pack_w2_kernel<<<(5 * 128 * 512 + 255) / 256, 256, 0, stream>>>(
      w4, apk4, 102, 459, 512, 128, 5, 9);
  pack_w2_kernel<<<(5 * 128 * 320 + 255) / 256, 256, 0, stream>>>(
      w5, apk5, 102, 306, 320, 128, 5, 3);
  // ---- gg2: 51->51, H 9->7, L=2048
  gg_mfma3_kernel<3, 64><<<dim3(32, 7, 8), 256, 0, stream>>>(
      z1, apk2, y2, st[2], 51, 51, 9, 2048, 32, 459, 512, 64);
  {
    unsigned int tot = 8u * 51 * 7 * 2048;
    bnrelu_kernel<<<(tot + 255) / 256, 256, 0, stream>>>(
        y2, st[2], gg[2], bbv[2], a3act, 51, 7 * 2048, 1.f / 114688.f, tot);
  }
  // ---- gg3: 51->51, H7, L=2048
  gg_mfma3_kernel<1, 64><<<dim3(32, 7, 8), 256, 0, stream>>>(
      a3act, apk3, y3, st[3], 51, 51, 7, 2048, 32, 153, 192, 64);
  {
    unsigned int tot = 8u * 51 * 7 * 512;
    bnrelu_pool_kernel<<<(tot + 255) / 256, 256, 0, stream>>>(
        y3, st[3], gg[3], bbv[3], z3, 51, 7, 2048, 1.f / 114688.f, tot);
  }
  // ---- gg4: 51->102, H 7->5, L=512 (2 co-groups)
  gg_mfma3_kernel<3, 32><<<dim3(32, 5, 8), 256, 0, stream>>>(
      z3, apk4, y4, st[4], 51, 102, 7, 512, 16, 459, 512, 128);
  {
    unsigned int tot = 8u * 102 * 5 * 512;
    bnrelu_kernel<<<(tot + 255) / 256, 256, 0, stream>>>(
        y4, st[4], gg[4], bbv[4], a5act, 102, 5 * 512, 1.f / 20480.f, tot);
  }
  // ---- gg5: 102->102, H5, L=512
  gg_mfma3_kernel<1, 32><<<dim3(32, 5, 8), 256, 0, stream>>>(
      a5act, apk5, y5, st[5], 102, 102, 5, 512, 16, 306, 320, 128);
  {
    unsigned int tot = 8u * 102 * 5 * 128;
    bnrelu_pool_kernel<<<(tot + 255) / 256, 256, 0, stream>>>(
        y5, st[5], gg[5], bbv[5], z5, 102, 5, 512, 1.f / 20480.f, tot);
  }
  // ---- gg6: 102->204, H 5->3, L=128
  gg_tail_kernel<3, 128, 2><<<dim3(102, 3, 8), 256, 0, stream>>>(
      z5, w6, y6, st[6], 102, 204, 5);
  {
    unsigned int tot = 8u * 204 * 3 * 128;
    bnrelu_kernel<<<(tot + 255) / 256, 256, 0, stream>>>(
        y6, st[6], gg[6], bbv[6], a6, 204, 3 * 128, 1.f / 3072.f, tot);
  }
  // ---- gg7: 204->204, H3, L=128
  gg_tail_kernel<1, 128, 2><<<dim3(102, 3, 8), 256, 0, stream>>>(
      a6, w7, y7, st[7], 204, 204, 3);
  {
    unsigned int tot = 8u * 204 * 3 * 128;
    bnrelu_kernel<<<(tot + 255) / 256, 256, 0, stream>>>(
        y7, st[7], gg[7], bbv[7], a7, 204, 3 * 128, 1.f / 3072.f, tot);
  }
  // ---- gg8: 204->204, H3, L=128
  gg_tail_kernel<1, 128, 2><<<dim3(102, 3, 8), 256, 0, stream>>>(
      a7, w8, y8, st[8], 204, 204, 3);
  {
    unsigned int tot = 8u * 204 * 3 * 32;
    bnrelu_pool_kernel<<<(tot + 255) / 256, 256, 0, stream>>>(
        y8, st[8], gg[8], bbv[8], z8, 204, 3, 128, 1.f / 3072.f, tot);
  }
  // ---- gg9: 204->408, H 3->1, L=32
  gg_tail_kernel<3, 32, 8><<<dim3(51, 1, 8), 256, 0, stream>>>(
      z8, w9, y9, st[9], 204, 408, 3);
  {
    unsigned int tot = 8u * 408 * 32;
    bnrelu_kernel<<<(tot + 255) / 256, 256, 0, stream>>>(
        y9, st[9], gg[9], bbv[9], a9, 408, 32, 1.f / 256.f, tot);
  }
  // ---- gg10: 408->408, H1, L=32
  gg_tail_kernel<1, 32, 8><<<dim3(51, 1, 8), 256, 0, stream>>>(
      a9, w10, y10, st[10], 408, 408, 1);
  // ---- final
  final_kernel<<<dim3(8), 256, 0, stream>>>(y10, st[10], gg[10], bbv[10], w11,
                                            (float*)d_out);
}

// Round 11
// 1672.213 us; speedup vs baseline: 1.3352x; 1.1217x over previous
//
#include <hip/hip_runtime.h>
#include <hip/hip_bf16.h>

#define EPSBN 2e-5f

typedef __attribute__((ext_vector_type(8))) short short8v;
typedef __attribute__((ext_vector_type(4))) float f32x4;

__device__ inline unsigned short f2bf(float f) {
  unsigned u = __float_as_uint(f);
  unsigned r = (u + 0x7FFFu + ((u >> 16) & 1u)) >> 16;
  return (unsigned short)r;
}
__device__ inline float bf2f(unsigned short h) {
  return __uint_as_float(((unsigned)h) << 16);
}
__device__ inline unsigned pkbf(float a, float b) {
  __hip_bfloat162 q = __float22bfloat162_rn(make_float2(a, b));
  return *reinterpret_cast<unsigned*>(&q);
}

// ---------------------------------------------------------------------------
// Padded x staging
// ---------------------------------------------------------------------------
constexpr int XPADL = 9984;
constexpr int XPADR = 14336;
constexpr int PROW = XPADL + 32768 + XPADR;  // 57088

__global__ __launch_bounds__(256) void pad_x_kernel(const float* __restrict__ x,
                                                    float* __restrict__ xp) {
  int i = blockIdx.x * 256 + threadIdx.x;
  if (i >= 8 * PROW) return;
  int b = i / PROW;
  int pos = i - b * PROW - XPADL;
  xp[i] = (pos >= 0 && pos < 32768) ? x[b * 32768 + pos] : 0.f;
}

// ---------------------------------------------------------------------------
// Lift conv body (dilation 2^S, scale 1/2^S) + pool4 + BN-stats.
// ---------------------------------------------------------------------------
template <int S>
__device__ __forceinline__ void lift_body(const float* __restrict__ xp,
                                          const float* __restrict__ w1,
                                          float* __restrict__ y1,
                                          float* __restrict__ st, int tile,
                                          int c, int b) {
  constexpr int d = 1 << S;
  constexpr float inv = 1.f / (float)d;
  const int l0 = tile * 4096;
  const int t = threadIdx.x;
  const int q = t & (d - 1);
  const int j = t >> S;
  const int base = l0 + q + ((j * 16) << S);
  const float* xrow = xp + b * PROW + XPADL;
  const float* wr = w1 + c * 79;

  float acc[16], win[16];
#pragma unroll
  for (int r = 0; r < 16; ++r) acc[r] = 0.f;
  int idx = base - 39 * d;
#pragma unroll
  for (int i = 0; i < 16; ++i) {
    win[i] = xrow[idx];
    idx += d;
  }
#pragma unroll
  for (int ko = 0; ko < 5; ++ko) {
#pragma unroll
    for (int kj = 0; kj < 16; ++kj) {
      const int k = ko * 16 + kj;
      const float wk = (k < 79) ? wr[k] : 0.f;
#pragma unroll
      for (int r = 0; r < 16; ++r)
        acc[r] = fmaf(wk, win[(kj + r) & 15], acc[r]);
      win[kj] = xrow[idx];
      idx += d;
    }
  }

  float ssum = 0.f, ssq = 0.f;
  float* yrow = y1 + (((size_t)b * 51 + c) * 9 + S) * 8192 + (l0 >> 2);
  if constexpr (S == 0) {
#pragma unroll
    for (int m = 0; m < 4; ++m) {
      float v = fmaxf(fmaxf(acc[4 * m], acc[4 * m + 1]),
                      fmaxf(acc[4 * m + 2], acc[4 * m + 3]));
      yrow[4 * t + m] = v;
      ssum += v;
      ssq += v * v;
    }
  } else if constexpr (S == 1) {
#pragma unroll
    for (int m = 0; m < 8; ++m) {
      float u = fmaxf(acc[2 * m], acc[2 * m + 1]);
      u = fmaxf(u, __shfl_xor(u, 1));
      if ((t & 1) == 0) {
        float v = u * inv;
        yrow[8 * j + m] = v;
        ssum += v;
        ssq += v * v;
      }
    }
  } else {
#pragma unroll
    for (int r = 0; r < 16; ++r) {
      float u = fmaxf(acc[r], __shfl_xor(acc[r], 1));
      u = fmaxf(u, __shfl_xor(u, 2));
      if ((t & 3) == 0) {
        float v = u * inv;
        yrow[(q >> 2) + ((j * 16 + r) << (S - 2))] = v;
        ssum += v;
        ssq += v * v;
      }
    }
  }
#pragma unroll
  for (int off = 32; off > 0; off >>= 1) {
    ssum += __shfl_down(ssum, off);
    ssq += __shfl_down(ssq, off);
  }
  __shared__ float rs[4], rq[4];
  const int wid = t >> 6;
  if ((t & 63) == 0) {
    rs[wid] = ssum;
    rq[wid] = ssq;
  }
  __syncthreads();
  if (t == 0) {
    atomicAdd(&st[c], rs[0] + rs[1] + rs[2] + rs[3]);
    atomicAdd(&st[512 + c], rq[0] + rq[1] + rq[2] + rq[3]);
  }
}

// One dispatch for all 9 scales: block-uniform switch on s.
__global__ __launch_bounds__(256) void lift_all_kernel(
    const float* __restrict__ xp, const float* __restrict__ w1,
    float* __restrict__ y1, float* __restrict__ st) {
  const int tile = blockIdx.x;
  const int cy = blockIdx.y;
  const int c = cy / 9;
  const int s = cy - 9 * c;
  const int b = blockIdx.z;
  switch (s) {
    case 0: lift_body<0>(xp, w1, y1, st, tile, c, b); break;
    case 1: lift_body<1>(xp, w1, y1, st, tile, c, b); break;
    case 2: lift_body<2>(xp, w1, y1, st, tile, c, b); break;
    case 3: lift_body<3>(xp, w1, y1, st, tile, c, b); break;
    case 4: lift_body<4>(xp, w1, y1, st, tile, c, b); break;
    case 5: lift_body<5>(xp, w1, y1, st, tile, c, b); break;
    case 6: lift_body<6>(xp, w1, y1, st, tile, c, b); break;
    case 7: lift_body<7>(xp, w1, y1, st, tile, c, b); break;
    case 8: lift_body<8>(xp, w1, y1, st, tile, c, b); break;
  }
}

// ---------------------------------------------------------------------------
// Per-channel sum/sumsq over [B,C,HL]; grid (C,B)
// ---------------------------------------------------------------------------
__global__ __launch_bounds__(256) void stats_kernel(
    const float* __restrict__ Y, float* __restrict__ st, int C, int HL) {
  const int c = blockIdx.x, b = blockIdx.y;
  const float* p = Y + ((size_t)b * C + c) * HL;
  float s = 0.f, q = 0.f;
  for (int i = threadIdx.x; i < HL; i += 256) {
    float v = p[i];
    s += v;
    q += v * v;
  }
#pragma unroll
  for (int off = 32; off > 0; off >>= 1) {
    s += __shfl_down(s, off, 64);
    q += __shfl_down(q, off, 64);
  }
  __shared__ float ls[4], lq[4];
  const int wid = threadIdx.x >> 6, lane = threadIdx.x & 63;
  if (lane == 0) { ls[wid] = s; lq[wid] = q; }
  __syncthreads();
  if (threadIdx.x == 0) {
    atomicAdd(&st[c], ls[0] + ls[1] + ls[2] + ls[3]);
    atomicAdd(&st[512 + c], lq[0] + lq[1] + lq[2] + lq[3]);
  }
}

// ---------------------------------------------------------------------------
// BN(train) + ReLU + pool4
// ---------------------------------------------------------------------------
__global__ __launch_bounds__(256) void bnrelu_pool_kernel(
    const float* __restrict__ Y, const float* __restrict__ st,
    const float* __restrict__ g, const float* __restrict__ bb,
    float* __restrict__ Z, int C, int H, int Lin, float invN,
    unsigned int total) {
  unsigned int idx = blockIdx.x * 256u + threadIdx.x;
  if (idx >= total) return;
  const unsigned int Lo = (unsigned int)(Lin >> 2);
  unsigned int lo = idx % Lo;
  unsigned int r1 = idx / Lo;
  unsigned int h = r1 % (unsigned int)H;
  unsigned int r2 = r1 / (unsigned int)H;
  unsigned int c = r2 % (unsigned int)C;
  unsigned int b = r2 / (unsigned int)C;
  float m = st[c] * invN;
  float v = st[512 + c] * invN - m * m;
  float sc = g[c] * rsqrtf(v + EPSBN);
  float bi = bb[c] - m * sc;
  const float* p = Y + (((size_t)b * C + c) * H + h) * Lin + 4u * lo;
  float a0 = p[0] * sc + bi, a1 = p[1] * sc + bi;
  float a2 = p[2] * sc + bi, a3 = p[3] * sc + bi;
  float r = fmaxf(fmaxf(a0, a1), fmaxf(a2, a3));
  Z[idx] = fmaxf(r, 0.f);
}

// ---------------------------------------------------------------------------
// BN(train) + ReLU, elementwise
// ---------------------------------------------------------------------------
__global__ __launch_bounds__(256) void bnrelu_kernel(
    const float* __restrict__ Y, const float* __restrict__ st,
    const float* __restrict__ g, const float* __restrict__ bb,
    float* __restrict__ A, int C, int HL, float invN, unsigned int total) {
  unsigned int idx = blockIdx.x * 256u + threadIdx.x;
  if (idx >= total) return;
  unsigned int c = (idx / (unsigned int)HL) % (unsigned int)C;
  float m = st[c] * invN;
  float v = st[512 + c] * invN - m * m;
  float sc = g[c] * rsqrtf(v + EPSBN);
  float bi = bb[c] - m * sc;
  A[idx] = fmaxf(fmaf(Y[idx], sc, bi), 0.f);
}

// ---------------------------------------------------------------------------
// Pack fp32 weights -> per-s split bf16 packs with 2^-(s+i) folded.
// ---------------------------------------------------------------------------
__global__ __launch_bounds__(256) void pack_w2_kernel(
    const float* __restrict__ W, short* __restrict__ A, int Co, int KTOT,
    int KPAD, int COPAD, int NS, int nk3) {
  int idx = blockIdx.x * 256 + threadIdx.x;
  const int CK = COPAD * KPAD;
  if (idx >= NS * CK) return;
  int s = idx / CK;
  int rem = idx - s * CK;
  int co = rem / KPAD;
  int kk = rem - co * KPAD;
  float v = 0.f;
  if (co < Co && kk < KTOT) {
    int i = (kk % nk3) / 3;
    float scale = __uint_as_float((unsigned)(127 - (s + i)) << 23);
    v = W[co * KTOT + kk] * scale;
  }
  unsigned short hi = f2bf(v);
  unsigned short lo = f2bf(v - bf2f(hi));
  A[(size_t)s * 2 * CK + co * KPAD + kk] = (short)hi;
  A[(size_t)s * 2 * CK + CK + co * KPAD + kk] = (short)lo;
}

// ---------------------------------------------------------------------------
// gg_mfma4: gg_mfma3 + register-prefetch pipeline.
// Chunk c+1's gathered B values and chunk c's A fragments are loaded into
// registers BEFORE the barrier; global latency hides behind MFMA + barriers.
// Numerics identical to R10 (A hi/lo split x single-RNE bf16 B).
// ---------------------------------------------------------------------------
template <int NKv, int LT>
__global__ __launch_bounds__(256) void gg_mfma4_kernel(
    const float* __restrict__ X, const short* __restrict__ Apk,
    float* __restrict__ Y, float* __restrict__ stOut, int Ci, int Co, int Hin,
    int L, int nL, int KTOT, int KPAD, int COPAD) {
  constexpr int T = LT / 16;
  constexpr int KO = 256 / LT;
  constexpr int RIT = 8 / KO;

  const int bx = blockIdx.x;
  const int lc = bx % nL;
  const int cog = bx / nL;
  const int s = blockIdx.y;
  const int b = blockIdx.z;
  const int Hout = Hin - NKv + 1;
  const int l0 = lc * LT;
  const int tid = threadIdx.x;
  const int lane = tid & 63;
  const int quad = lane >> 4;
  const int m0 = lane & 15;
  const int wv = tid >> 6;
  const int coBase = cog * 64 + wv * 16;

  __shared__ __align__(16) short Bh[LT * 72];
  __shared__ int roT[512];
  __shared__ int shT[512];

  for (int kk = tid; kk < KPAD; kk += 256) {
    int ro = 0, sh = -(1 << 30);
    if (kk < KTOT) {
      int ci = kk / (3 * NKv);
      int rem = kk - ci * (3 * NKv);
      int i = rem / 3;
      int k = rem - 3 * i;
      ro = (ci * Hin + s + i) * L;
      sh = (k - 1) * (1 << (s + i));
    }
    roT[kk] = ro;
    shT[kk] = sh;
  }
  __syncthreads();

  f32x4 acc[T];
#pragma unroll
  for (int t = 0; t < T; ++t) acc[t] = (f32x4){0.f, 0.f, 0.f, 0.f};

  const short* ApkS = Apk + (size_t)s * 2 * COPAD * KPAD;
  const short* arowH = ApkS + (size_t)(coBase + m0) * KPAD;
  const short* arowL = arowH + (size_t)COPAD * KPAD;
  const float* Xb = X + (size_t)b * Ci * Hin * L;

  const int lB = tid & (LT - 1);
  const int oc0 = tid / LT;
  const int nch = (KTOT + 63) >> 6;

  float vcur[RIT][8];
  auto gather = [&](int c0, float (&vv)[RIT][8]) {
#pragma unroll
    for (int r = 0; r < RIT; ++r) {
      const int oct = oc0 + KO * r;
      const int kkb = (c0 << 6) + oct * 8;
#pragma unroll
      for (int j = 0; j < 8; ++j) {
        const int kk = kkb + j;
        const int pos = l0 + lB + shT[kk];
        const int posc = min(max(pos, 0), L - 1);
        float x = Xb[roT[kk] + posc];
        vv[r][j] = ((unsigned)pos < (unsigned)L) ? x : 0.f;
      }
    }
  };

  gather(0, vcur);
  for (int c0 = 0; c0 < nch; ++c0) {
    // ---- pack + write current chunk to LDS (one b128 per thread per RIT)
#pragma unroll
    for (int r = 0; r < RIT; ++r) {
      const int oct = oc0 + KO * r;
      uint4 pk;
      pk.x = pkbf(vcur[r][0], vcur[r][1]);
      pk.y = pkbf(vcur[r][2], vcur[r][3]);
      pk.z = pkbf(vcur[r][4], vcur[r][5]);
      pk.w = pkbf(vcur[r][6], vcur[r][7]);
      *(uint4*)(Bh + lB * 72 + oct * 8) = pk;
    }
    // ---- prefetch next chunk's gathers + this chunk's A fragments
    float vnext[RIT][8];
    if (c0 + 1 < nch) gather(c0 + 1, vnext);
    const int a0 = (c0 << 6) + quad * 8;
    short8v ah0 = *(const short8v*)(arowH + a0);
    short8v al0 = *(const short8v*)(arowL + a0);
    short8v ah1 = *(const short8v*)(arowH + a0 + 32);
    short8v al1 = *(const short8v*)(arowL + a0 + 32);
    __syncthreads();
    // ---- MFMA phase
#pragma unroll
    for (int t = 0; t < T; ++t) {
      const int l = m0 + 16 * t;
      short8v b0 = *(const short8v*)(Bh + l * 72 + quad * 8);
      short8v b1 = *(const short8v*)(Bh + l * 72 + 32 + quad * 8);
      acc[t] = __builtin_amdgcn_mfma_f32_16x16x32_bf16(ah0, b0, acc[t], 0, 0, 0);
      acc[t] = __builtin_amdgcn_mfma_f32_16x16x32_bf16(al0, b0, acc[t], 0, 0, 0);
      acc[t] = __builtin_amdgcn_mfma_f32_16x16x32_bf16(ah1, b1, acc[t], 0, 0, 0);
      acc[t] = __builtin_amdgcn_mfma_f32_16x16x32_bf16(al1, b1, acc[t], 0, 0, 0);
    }
    __syncthreads();
    if (c0 + 1 < nch) {
#pragma unroll
      for (int r = 0; r < RIT; ++r)
#pragma unroll
        for (int j = 0; j < 8; ++j) vcur[r][j] = vnext[r][j];
    }
  }

  // ---- epilogue: store + fused stats
#pragma unroll
  for (int reg = 0; reg < 4; ++reg) {
    const int co = coBase + quad * 4 + reg;
    if (co < Co) {
      float* yp = Y + (((size_t)b * Co + co) * Hout + s) * L + l0;
#pragma unroll
      for (int t = 0; t < T; ++t) yp[m0 + 16 * t] = acc[t][reg];
    }
  }
  if (stOut) {
#pragma unroll
    for (int reg = 0; reg < 4; ++reg) {
      float s1 = 0.f, s2 = 0.f;
#pragma unroll
      for (int t = 0; t < T; ++t) {
        s1 += acc[t][reg];
        s2 += acc[t][reg] * acc[t][reg];
      }
#pragma unroll
      for (int off = 1; off < 16; off <<= 1) {
        s1 += __shfl_xor(s1, off);
        s2 += __shfl_xor(s2, off);
      }
      const int co = coBase + quad * 4 + reg;
      if (m0 == 0 && co < Co) {
        atomicAdd(&stOut[co], s1);
        atomicAdd(&stOut[512 + co], s2);
      }
    }
  }
}

// ---------------------------------------------------------------------------
// gg_tail: no-LDS GConvGG for small stages (input pre-activated)
// ---------------------------------------------------------------------------
template <int NK, int L, int COSUB>
__global__ __launch_bounds__(256) void gg_tail_kernel(
    const float* __restrict__ X, const float* __restrict__ W,
    float* __restrict__ Y, float* __restrict__ stOut, int Ci, int Co,
    int Hin) {
  const int l = threadIdx.x % L;
  const int cs = threadIdx.x / L;
  const int co = blockIdx.x * COSUB + cs;
  const int s = blockIdx.y;
  const int b = blockIdx.z;
  const int Hout = Hin - NK + 1;

  float acc[NK];
#pragma unroll
  for (int i = 0; i < NK; ++i) acc[i] = 0.f;

  const float* wbase = W + (size_t)co * Ci * NK * 3;
  const float* xbase = X + ((size_t)b * Ci * Hin + s) * L;

  for (int ci = 0; ci < Ci; ++ci) {
    const float* wp = wbase + ci * (NK * 3);
    const float* xr = xbase + ci * (Hin * L);
#pragma unroll
    for (int i = 0; i < NK; ++i) {
      const int d = 1 << (s + i);
      const float* row = xr + i * L;
      float xm = (l >= d) ? row[l - d] : 0.f;
      float xc = row[l];
      float xp = (l + d < L) ? row[l + d] : 0.f;
      acc[i] = fmaf(wp[3 * i], xm,
                    fmaf(wp[3 * i + 1], xc, fmaf(wp[3 * i + 2], xp, acc[i])));
    }
  }
  float out = 0.f;
#pragma unroll
  for (int i = 0; i < NK; ++i) {
    float invd = __uint_as_float((unsigned)(127 - (s + i)) << 23);
    out = fmaf(acc[i], invd, out);
  }
  Y[(((size_t)b * Co + co) * Hout + s) * L + l] = out;

  float s1 = out, s2 = out * out;
  constexpr int RED = (L < 64) ? L : 64;
#pragma unroll
  for (int off = RED / 2; off > 0; off >>= 1) {
    s1 += __shfl_xor(s1, off);
    s2 += __shfl_xor(s2, off);
  }
  if ((threadIdx.x & (RED - 1)) == 0) {
    atomicAdd(&stOut[co], s1);
    atomicAdd(&stOut[512 + co], s2);
  }
}

// ---------------------------------------------------------------------------
// gg_tail_split: K-split tail for the tiny-grid stages (gg9/gg10, Hout=1,s=0).
// Each block covers ci in [blockIdx.y*ciPer, +ciPer); outputs atomicAdd into
// pre-zeroed Y. Stats via separate stats_kernel pass.
// ---------------------------------------------------------------------------
template <int NK, int L, int COSUB>
__global__ __launch_bounds__(256) void gg_tail_split_kernel(
    const float* __restrict__ X, const float* __restrict__ W,
    float* __restrict__ Y, int Ci, int Co, int Hin, int ciPer) {
  const int l = threadIdx.x % L;
  const int cs = threadIdx.x / L;
  const int co = blockIdx.x * COSUB + cs;
  const int b = blockIdx.z;
  const int ciBeg = blockIdx.y * ciPer;
  const int ciEnd = min(Ci, ciBeg + ciPer);

  float acc[NK];
#pragma unroll
  for (int i = 0; i < NK; ++i) acc[i] = 0.f;

  const float* wbase = W + (size_t)co * Ci * NK * 3;
  const float* xbase = X + (size_t)b * Ci * Hin * L;

  for (int ci = ciBeg; ci < ciEnd; ++ci) {
    const float* wp = wbase + ci * (NK * 3);
    const float* xr = xbase + ci * (Hin * L);
#pragma unroll
    for (int i = 0; i < NK; ++i) {
      const int d = 1 << i;
      const float* row = xr + i * L;
      float xm = (l >= d) ? row[l - d] : 0.f;
      float xc = row[l];
      float xp = (l + d < L) ? row[l + d] : 0.f;
      acc[i] = fmaf(wp[3 * i], xm,
                    fmaf(wp[3 * i + 1], xc, fmaf(wp[3 * i + 2], xp, acc[i])));
    }
  }
  float out = 0.f;
#pragma unroll
  for (int i = 0; i < NK; ++i) {
    float invd = __uint_as_float((unsigned)(127 - i) << 23);
    out = fmaf(acc[i], invd, out);
  }
  atomicAdd(&Y[((size_t)b * Co + co) * L + l], out);
}

// ---------------------------------------------------------------------------
// Final: bn10+relu, mean over L, classifier
// ---------------------------------------------------------------------------
__global__ __launch_bounds__(256) void final_kernel(
    const float* __restrict__ Y, const float* __restrict__ st,
    const float* __restrict__ g, const float* __restrict__ bb,
    const float* __restrict__ w11, float* __restrict__ out) {
  const int b = blockIdx.x;
  const int tid = threadIdx.x;
  __shared__ float tch[408];
  for (int c = tid; c < 408; c += 256) {
    float m = st[c] * (1.f / 256.f);
    float v = st[512 + c] * (1.f / 256.f) - m * m;
    float sc = g[c] * rsqrtf(v + EPSBN);
    float bi = bb[c] - m * sc;
    const float* p = Y + ((size_t)b * 408 + c) * 32;
    float ssum = 0.f;
#pragma unroll
    for (int l = 0; l < 32; ++l) ssum += fmaxf(p[l] * sc + bi, 0.f);
    tch[c] = ssum * (1.f / 32.f);
  }
  __syncthreads();
  if (tid < 10) {
    float ssum = 0.f;
    for (int c = 0; c < 408; ++c) ssum += w11[tid * 408 + c] * tch[c];
    out[b * 10 + tid] = ssum;
  }
}

// ---------------------------------------------------------------------------
extern "C" void kernel_launch(void* const* d_in, const int* in_sizes, int n_in,
                              void* d_out, int out_size, void* d_ws,
                              size_t ws_size, hipStream_t stream) {
  const float* x = (const float*)d_in[0];
  const float* w1 = (const float*)d_in[1];
  const float* w2 = (const float*)d_in[2];
  const float* w3 = (const float*)d_in[3];
  const float* w4 = (const float*)d_in[4];
  const float* w5 = (const float*)d_in[5];
  const float* w6 = (const float*)d_in[6];
  const float* w7 = (const float*)d_in[7];
  const float* w8 = (const float*)d_in[8];
  const float* w9 = (const float*)d_in[9];
  const float* w10 = (const float*)d_in[10];
  const float* w11 = (const float*)d_in[11];
  const float* gg[11];
  const float* bbv[11];
  for (int i = 1; i <= 10; ++i) {
    gg[i] = (const float*)d_in[12 + 2 * (i - 1)];
    bbv[i] = (const float*)d_in[12 + 2 * (i - 1) + 1];
  }

  float* ws = (float*)d_ws;
  const size_t AR0 = 0;
  const size_t AR1 = 30081024;
  const size_t STATS = 37601280;
  float* y1 = ws + AR0;
  float* xpad = ws + AR1;
  float* z1 = ws + AR1;
  float* y2 = ws + AR0;
  float* y3 = ws + AR0 + 5849088;
  float* a3act = ws + AR1;
  float* z3 = ws + AR1;
  float* y4 = ws + AR0;
  float* y5 = ws + AR0 + 2088960;
  float* a5act = ws + AR1 + 1500000;
  float* z5 = ws + AR1;
  float* a6 = ws + AR1 + 522240;
  float* a7 = ws + AR1 + 1148928;
  float* z8 = ws + AR1;
  float* a9 = ws + AR1 + 1775616;
  float* y6 = ws + AR0;
  float* y7 = ws + AR0 + 626688;
  float* y8 = ws + AR0 + 1253376;
  float* y9 = ws + AR0;
  float* y10 = ws + AR0 + 104448;
  short* apk2 = (short*)(ws + 12000000);
  short* apk3 = apk2 + 7 * 2 * 64 * 512;
  short* apk4 = apk3 + 7 * 2 * 64 * 192;
  short* apk5 = apk4 + 5 * 2 * 128 * 512;
  float* st[11];
  for (int i = 1; i <= 10; ++i) st[i] = ws + STATS + (size_t)(i - 1) * 1024;

  hipMemsetAsync((void*)(ws + STATS), 0, 10 * 1024 * sizeof(float), stream);

  // ---- pad + lift (single dispatch, stats1 fused)
  pad_x_kernel<<<(8 * PROW + 255) / 256, 256, 0, stream>>>(x, xpad);
  lift_all_kernel<<<dim3(8, 459, 8), 256, 0, stream>>>(xpad, w1, y1, st[1]);
  {
    unsigned int tot = 8u * 51 * 9 * 2048;
    bnrelu_pool_kernel<<<(tot + 255) / 256, 256, 0, stream>>>(
        y1, st[1], gg[1], bbv[1], z1, 51, 9, 8192, 1.f / 589824.f, tot);
  }
  // ---- per-s weight packs
  pack_w2_kernel<<<(7 * 64 * 512 + 255) / 256, 256, 0, stream>>>(
      w2, apk2, 51, 459, 512, 64, 7, 9);
  pack_w2_kernel<<<(7 * 64 * 192 + 255) / 256, 256, 0, stream>>>(
      w3, apk3, 51, 153, 192, 64, 7, 3);
  pack_w2_kernel<<<(5 * 128 * 512 + 255) / 256, 256, 0, stream>>>(
      w4, apk4, 102, 459, 512, 128, 5, 9);
  pack_w2_kernel<<<(5 * 128 * 320 + 255) / 256, 256, 0, stream>>>(
      w5, apk5, 102, 306, 320, 128, 5, 3);
  // ---- gg2: 51->51, H 9->7, L=2048
  gg_mfma4_kernel<3, 64><<<dim3(32, 7, 8), 256, 0, stream>>>(
      z1, apk2, y2, st[2], 51, 51, 9, 2048, 32, 459, 512, 64);
  {
    unsigned int tot = 8u * 51 * 7 * 2048;
    bnrelu_kernel<<<(tot + 255) / 256, 256, 0, stream>>>(
        y2, st[2], gg[2], bbv[2], a3act, 51, 7 * 2048, 1.f / 114688.f, tot);
  }
  // ---- gg3: 51->51, H7, L=2048
  gg_mfma4_kernel<1, 64><<<dim3(32, 7, 8), 256, 0, stream>>>(
      a3act, apk3, y3, st[3], 51, 51, 7, 2048, 32, 153, 192, 64);
  {
    unsigned int tot = 8u * 51 * 7 * 512;
    bnrelu_pool_kernel<<<(tot + 255) / 256, 256, 0, stream>>>(
        y3, st[3], gg[3], bbv[3], z3, 51, 7, 2048, 1.f / 114688.f, tot);
  }
  // ---- gg4: 51->102, H 7->5, L=512
  gg_mfma4_kernel<3, 32><<<dim3(32, 5, 8), 256, 0, stream>>>(
      z3, apk4, y4, st[4], 51, 102, 7, 512, 16, 459, 512, 128);
  {
    unsigned int tot = 8u * 102 * 5 * 512;
    bnrelu_kernel<<<(tot + 255) / 256, 256, 0, stream>>>(
        y4, st[4], gg[4], bbv[4], a5act, 102, 5 * 512, 1.f / 20480.f, tot);
  }
  // ---- gg5: 102->102, H5, L=512
  gg_mfma4_kernel<1, 32><<<dim3(32, 5, 8), 256, 0, stream>>>(
      a5act, apk5, y5, st[5], 102, 102, 5, 512, 16, 306, 320, 128);
  {
    unsigned int tot = 8u * 102 * 5 * 128;
    bnrelu_pool_kernel<<<(tot + 255) / 256, 256, 0, stream>>>(
        y5, st[5], gg[5], bbv[5], z5, 102, 5, 512, 1.f / 20480.f, tot);
  }
  // ---- gg6: 102->204, H 5->3, L=128
  gg_tail_kernel<3, 128, 2><<<dim3(102, 3, 8), 256, 0, stream>>>(
      z5, w6, y6, st[6], 102, 204, 5);
  {
    unsigned int tot = 8u * 204 * 3 * 128;
    bnrelu_kernel<<<(tot + 255) / 256, 256, 0, stream>>>(
        y6, st[6], gg[6], bbv[6], a6, 204, 3 * 128, 1.f / 3072.f, tot);
  }
  // ---- gg7: 204->204, H3, L=128
  gg_tail_kernel<1, 128, 2><<<dim3(102, 3, 8), 256, 0, stream>>>(
      a6, w7, y7, st[7], 204, 204, 3);
  {
    unsigned int tot = 8u * 204 * 3 * 128;
    bnrelu_kernel<<<(tot + 255) / 256, 256, 0, stream>>>(
        y7, st[7], gg[7], bbv[7], a7, 204, 3 * 128, 1.f / 3072.f, tot);
  }
  // ---- gg8: 204->204, H3, L=128
  gg_tail_kernel<1, 128, 2><<<dim3(102, 3, 8), 256, 0, stream>>>(
      a7, w8, y8, st[8], 204, 204, 3);
  {
    unsigned int tot = 8u * 204 * 3 * 32;
    bnrelu_pool_kernel<<<(tot + 255) / 256, 256, 0, stream>>>(
        y8, st[8], gg[8], bbv[8], z8, 204, 3, 128, 1.f / 3072.f, tot);
  }
  // ---- gg9: 204->408, H 3->1, L=32 (K-split x4, atomic accumulate)
  hipMemsetAsync((void*)y9, 0, 2 * 104448 * sizeof(float), stream);
  gg_tail_split_kernel<3, 32, 8><<<dim3(51, 4, 8), 256, 0, stream>>>(
      z8, w9, y9, 204, 408, 3, 51);
  stats_kernel<<<dim3(408, 8), 256, 0, stream>>>(y9, st[9], 408, 32);
  {
    unsigned int tot = 8u * 408 * 32;
    bnrelu_kernel<<<(tot + 255) / 256, 256, 0, stream>>>(
        y9, st[9], gg[9], bbv[9], a9, 408, 32, 1.f / 256.f, tot);
  }
  // ---- gg10: 408->408, H1, L=32 (K-split x4)
  gg_tail_split_kernel<1, 32, 8><<<dim3(51, 4, 8), 256, 0, stream>>>(
      a9, w10, y10, 408, 408, 1, 102);
  stats_kernel<<<dim3(408, 8), 256, 0, stream>>>(y10, st[10], 408, 32);
  // ---- final
  final_kernel<<<dim3(8), 256, 0, stream>>>(y10, st[10], gg[10], bbv[10], w11,
                                            (float*)d_out);
}

// Round 12
// 1480.310 us; speedup vs baseline: 1.5082x; 1.1296x over previous
//
#include <hip/hip_runtime.h>
#include <hip/hip_bf16.h>

#define EPSBN 2e-5f

typedef __attribute__((ext_vector_type(8))) short short8v;
typedef __attribute__((ext_vector_type(4))) float f32x4;

__device__ inline unsigned short f2bf(float f) {
  unsigned u = __float_as_uint(f);
  unsigned r = (u + 0x7FFFu + ((u >> 16) & 1u)) >> 16;
  return (unsigned short)r;
}
__device__ inline float bf2f(unsigned short h) {
  return __uint_as_float(((unsigned)h) << 16);
}
__device__ inline unsigned pkbf(float a, float b) {
  __hip_bfloat162 q = __float22bfloat162_rn(make_float2(a, b));
  return *reinterpret_cast<unsigned*>(&q);
}

// ---------------------------------------------------------------------------
// Padded x staging
// ---------------------------------------------------------------------------
constexpr int XPADL = 9984;
constexpr int XPADR = 14336;
constexpr int PROW = XPADL + 32768 + XPADR;  // 57088

__global__ __launch_bounds__(256) void pad_x_kernel(const float* __restrict__ x,
                                                    float* __restrict__ xp) {
  int i = blockIdx.x * 256 + threadIdx.x;
  if (i >= 8 * PROW) return;
  int b = i / PROW;
  int pos = i - b * PROW - XPADL;
  xp[i] = (pos >= 0 && pos < 32768) ? x[b * 32768 + pos] : 0.f;
}

// ---------------------------------------------------------------------------
// Pack w1 [51][79] -> per-s split bf16: Apk1[s][plane hi/lo][64 co][96 k],
// with 1/2^s folded; zero-padded (co>=51 or k>=79 -> 0).
// ---------------------------------------------------------------------------
__global__ __launch_bounds__(256) void pack_w1_kernel(
    const float* __restrict__ W, short* __restrict__ A) {
  int idx = blockIdx.x * 256 + threadIdx.x;
  if (idx >= 9 * 64 * 96) return;
  int s = idx / (64 * 96);
  int rem = idx - s * 64 * 96;
  int co = rem / 96;
  int k = rem - co * 96;
  float v = 0.f;
  if (co < 51 && k < 79)
    v = W[co * 79 + k] * __uint_as_float((unsigned)(127 - s) << 23);
  unsigned short hi = f2bf(v);
  unsigned short lo = f2bf(v - bf2f(hi));
  A[(size_t)s * 2 * 64 * 96 + co * 96 + k] = (short)hi;
  A[(size_t)s * 2 * 64 * 96 + 64 * 96 + co * 96 + k] = (short)lo;
}

// ---------------------------------------------------------------------------
// lift_mfma: lift conv K=79 as bf16-MFMA GEMM + fused pool4.
// Per (b, s, 64-l chunk): C[co,l] = sum_k w1s[co,k] * xpad[l + (k-39)*d].
// M=64 co (4 waves x 16), K=96 (3 steps of 32), N=64 l (4 n-tiles/wave).
// Both operands hi/lo split -> 3 MFMA terms (err ~2^-16, fp32-grade).
// B staged in LDS pitch 104 shorts (stride 52 words, gcd 4 -> uniform 8-deep
// banks for b128 write+read). Gathers from xpad: coalesced in l, no bounds.
// D layout col=lane&15=n, row=quad*4+reg=co (R8-verified); pool4 via
// shfl_xor(1,2); stats NOT fused (separate stats pass) to avoid atomic storm.
// ---------------------------------------------------------------------------
__global__ __launch_bounds__(256) void lift_mfma_kernel(
    const float* __restrict__ xp, const short* __restrict__ Apk1,
    float* __restrict__ y1) {
  constexpr int P = 104;  // LDS pitch (shorts)
  const int lc = blockIdx.x;
  const int s = blockIdx.y;
  const int b = blockIdx.z;
  const int d = 1 << s;
  const int l0 = lc * 64;
  const int tid = threadIdx.x;
  const int lane = tid & 63;
  const int quad = lane >> 4;
  const int n0 = lane & 15;
  const int wv = tid >> 6;
  const int coBase = wv * 16;

  __shared__ __align__(16) short Bh[64 * P];
  __shared__ __align__(16) short Bl[64 * P];

  const float* xrow = xp + b * PROW + XPADL;

  // ---- stage B: thread = (n, oct-group); 12 octs of 8 k; trunc hi/lo split
  const int nB = tid & 63;
  const int og = tid >> 6;
#pragma unroll
  for (int r = 0; r < 3; ++r) {
    const int oct = og + 4 * r;  // 0..11
    const int kb = oct * 8;
    float v[8];
#pragma unroll
    for (int j = 0; j < 8; ++j) v[j] = xrow[l0 + nB + (kb + j - 39) * d];
    unsigned h[8], lo[8];
#pragma unroll
    for (int j = 0; j < 8; ++j) {
      unsigned u = __float_as_uint(v[j]);
      h[j] = u >> 16;
      float lof = v[j] - __uint_as_float(u & 0xffff0000u);
      lo[j] = __float_as_uint(lof) >> 16;
    }
    uint4 ph, pl;
    ph.x = h[0] | (h[1] << 16);
    ph.y = h[2] | (h[3] << 16);
    ph.z = h[4] | (h[5] << 16);
    ph.w = h[6] | (h[7] << 16);
    pl.x = lo[0] | (lo[1] << 16);
    pl.y = lo[2] | (lo[3] << 16);
    pl.z = lo[4] | (lo[5] << 16);
    pl.w = lo[6] | (lo[7] << 16);
    *(uint4*)(Bh + nB * P + kb) = ph;
    *(uint4*)(Bl + nB * P + kb) = pl;
  }

  const short* ApkS = Apk1 + (size_t)s * 2 * 64 * 96;
  const short* arowH = ApkS + (coBase + n0) * 96;
  const short* arowL = arowH + 64 * 96;

  __syncthreads();

  f32x4 acc[4];
#pragma unroll
  for (int t = 0; t < 4; ++t) acc[t] = (f32x4){0.f, 0.f, 0.f, 0.f};

#pragma unroll
  for (int ks = 0; ks < 3; ++ks) {
    short8v ah = *(const short8v*)(arowH + ks * 32 + quad * 8);
    short8v al = *(const short8v*)(arowL + ks * 32 + quad * 8);
#pragma unroll
    for (int t = 0; t < 4; ++t) {
      const int n = n0 + 16 * t;
      short8v bh = *(const short8v*)(Bh + n * P + ks * 32 + quad * 8);
      short8v bl = *(const short8v*)(Bl + n * P + ks * 32 + quad * 8);
      acc[t] = __builtin_amdgcn_mfma_f32_16x16x32_bf16(ah, bh, acc[t], 0, 0, 0);
      acc[t] = __builtin_amdgcn_mfma_f32_16x16x32_bf16(ah, bl, acc[t], 0, 0, 0);
      acc[t] = __builtin_amdgcn_mfma_f32_16x16x32_bf16(al, bh, acc[t], 0, 0, 0);
    }
  }

  // ---- pool4 over n + store (scale already folded into weights)
#pragma unroll
  for (int reg = 0; reg < 4; ++reg) {
    const int co = coBase + quad * 4 + reg;
#pragma unroll
    for (int t = 0; t < 4; ++t) {
      float u = acc[t][reg];
      u = fmaxf(u, __shfl_xor(u, 1));
      u = fmaxf(u, __shfl_xor(u, 2));
      if ((n0 & 3) == 0 && co < 51) {
        const int l1 = (l0 >> 2) + t * 4 + (n0 >> 2);
        y1[(((size_t)b * 51 + co) * 9 + s) * 8192 + l1] = u;
      }
    }
  }
}

// ---------------------------------------------------------------------------
// Per-channel sum/sumsq over [B,C,HL]; grid (C,B)
// ---------------------------------------------------------------------------
__global__ __launch_bounds__(256) void stats_kernel(
    const float* __restrict__ Y, float* __restrict__ st, int C, int HL) {
  const int c = blockIdx.x, b = blockIdx.y;
  const float* p = Y + ((size_t)b * C + c) * HL;
  float s = 0.f, q = 0.f;
  for (int i = threadIdx.x; i < HL; i += 256) {
    float v = p[i];
    s += v;
    q += v * v;
  }
#pragma unroll
  for (int off = 32; off > 0; off >>= 1) {
    s += __shfl_down(s, off, 64);
    q += __shfl_down(q, off, 64);
  }
  __shared__ float ls[4], lq[4];
  const int wid = threadIdx.x >> 6, lane = threadIdx.x & 63;
  if (lane == 0) { ls[wid] = s; lq[wid] = q; }
  __syncthreads();
  if (threadIdx.x == 0) {
    atomicAdd(&st[c], ls[0] + ls[1] + ls[2] + ls[3]);
    atomicAdd(&st[512 + c], lq[0] + lq[1] + lq[2] + lq[3]);
  }
}

// ---------------------------------------------------------------------------
// BN(train) + ReLU + pool4
// ---------------------------------------------------------------------------
__global__ __launch_bounds__(256) void bnrelu_pool_kernel(
    const float* __restrict__ Y, const float* __restrict__ st,
    const float* __restrict__ g, const float* __restrict__ bb,
    float* __restrict__ Z, int C, int H, int Lin, float invN,
    unsigned int total) {
  unsigned int idx = blockIdx.x * 256u + threadIdx.x;
  if (idx >= total) return;
  const unsigned int Lo = (unsigned int)(Lin >> 2);
  unsigned int lo = idx % Lo;
  unsigned int r1 = idx / Lo;
  unsigned int h = r1 % (unsigned int)H;
  unsigned int r2 = r1 / (unsigned int)H;
  unsigned int c = r2 % (unsigned int)C;
  unsigned int b = r2 / (unsigned int)C;
  float m = st[c] * invN;
  float v = st[512 + c] * invN - m * m;
  float sc = g[c] * rsqrtf(v + EPSBN);
  float bi = bb[c] - m * sc;
  const float* p = Y + (((size_t)b * C + c) * H + h) * Lin + 4u * lo;
  float a0 = p[0] * sc + bi, a1 = p[1] * sc + bi;
  float a2 = p[2] * sc + bi, a3 = p[3] * sc + bi;
  float r = fmaxf(fmaxf(a0, a1), fmaxf(a2, a3));
  Z[idx] = fmaxf(r, 0.f);
}

// ---------------------------------------------------------------------------
// BN(train) + ReLU, elementwise
// ---------------------------------------------------------------------------
__global__ __launch_bounds__(256) void bnrelu_kernel(
    const float* __restrict__ Y, const float* __restrict__ st,
    const float* __restrict__ g, const float* __restrict__ bb,
    float* __restrict__ A, int C, int HL, float invN, unsigned int total) {
  unsigned int idx = blockIdx.x * 256u + threadIdx.x;
  if (idx >= total) return;
  unsigned int c = (idx / (unsigned int)HL) % (unsigned int)C;
  float m = st[c] * invN;
  float v = st[512 + c] * invN - m * m;
  float sc = g[c] * rsqrtf(v + EPSBN);
  float bi = bb[c] - m * sc;
  A[idx] = fmaxf(fmaf(Y[idx], sc, bi), 0.f);
}

// ---------------------------------------------------------------------------
// Pack fp32 weights -> per-s split bf16 packs with 2^-(s+i) folded.
// ---------------------------------------------------------------------------
__global__ __launch_bounds__(256) void pack_w2_kernel(
    const float* __restrict__ W, short* __restrict__ A, int Co, int KTOT,
    int KPAD, int COPAD, int NS, int nk3) {
  int idx = blockIdx.x * 256 + threadIdx.x;
  const int CK = COPAD * KPAD;
  if (idx >= NS * CK) return;
  int s = idx / CK;
  int rem = idx - s * CK;
  int co = rem / KPAD;
  int kk = rem - co * KPAD;
  float v = 0.f;
  if (co < Co && kk < KTOT) {
    int i = (kk % nk3) / 3;
    float scale = __uint_as_float((unsigned)(127 - (s + i)) << 23);
    v = W[co * KTOT + kk] * scale;
  }
  unsigned short hi = f2bf(v);
  unsigned short lo = f2bf(v - bf2f(hi));
  A[(size_t)s * 2 * CK + co * KPAD + kk] = (short)hi;
  A[(size_t)s * 2 * CK + CK + co * KPAD + kk] = (short)lo;
}

// ---------------------------------------------------------------------------
// gg_mfma4: register-prefetch pipelined bf16-MFMA GConvGG (R11, unchanged).
// ---------------------------------------------------------------------------
template <int NKv, int LT>
__global__ __launch_bounds__(256) void gg_mfma4_kernel(
    const float* __restrict__ X, const short* __restrict__ Apk,
    float* __restrict__ Y, float* __restrict__ stOut, int Ci, int Co, int Hin,
    int L, int nL, int KTOT, int KPAD, int COPAD) {
  constexpr int T = LT / 16;
  constexpr int KO = 256 / LT;
  constexpr int RIT = 8 / KO;

  const int bx = blockIdx.x;
  const int lc = bx % nL;
  const int cog = bx / nL;
  const int s = blockIdx.y;
  const int b = blockIdx.z;
  const int Hout = Hin - NKv + 1;
  const int l0 = lc * LT;
  const int tid = threadIdx.x;
  const int lane = tid & 63;
  const int quad = lane >> 4;
  const int m0 = lane & 15;
  const int wv = tid >> 6;
  const int coBase = cog * 64 + wv * 16;

  __shared__ __align__(16) short Bh[LT * 72];
  __shared__ int roT[512];
  __shared__ int shT[512];

  for (int kk = tid; kk < KPAD; kk += 256) {
    int ro = 0, sh = -(1 << 30);
    if (kk < KTOT) {
      int ci = kk / (3 * NKv);
      int rem = kk - ci * (3 * NKv);
      int i = rem / 3;
      int k = rem - 3 * i;
      ro = (ci * Hin + s + i) * L;
      sh = (k - 1) * (1 << (s + i));
    }
    roT[kk] = ro;
    shT[kk] = sh;
  }
  __syncthreads();

  f32x4 acc[T];
#pragma unroll
  for (int t = 0; t < T; ++t) acc[t] = (f32x4){0.f, 0.f, 0.f, 0.f};

  const short* ApkS = Apk + (size_t)s * 2 * COPAD * KPAD;
  const short* arowH = ApkS + (size_t)(coBase + m0) * KPAD;
  const short* arowL = arowH + (size_t)COPAD * KPAD;
  const float* Xb = X + (size_t)b * Ci * Hin * L;

  const int lB = tid & (LT - 1);
  const int oc0 = tid / LT;
  const int nch = (KTOT + 63) >> 6;

  float vcur[RIT][8];
  auto gather = [&](int c0, float (&vv)[RIT][8]) {
#pragma unroll
    for (int r = 0; r < RIT; ++r) {
      const int oct = oc0 + KO * r;
      const int kkb = (c0 << 6) + oct * 8;
#pragma unroll
      for (int j = 0; j < 8; ++j) {
        const int kk = kkb + j;
        const int pos = l0 + lB + shT[kk];
        const int posc = min(max(pos, 0), L - 1);
        float x = Xb[roT[kk] + posc];
        vv[r][j] = ((unsigned)pos < (unsigned)L) ? x : 0.f;
      }
    }
  };

  gather(0, vcur);
  for (int c0 = 0; c0 < nch; ++c0) {
#pragma unroll
    for (int r = 0; r < RIT; ++r) {
      const int oct = oc0 + KO * r;
      uint4 pk;
      pk.x = pkbf(vcur[r][0], vcur[r][1]);
      pk.y = pkbf(vcur[r][2], vcur[r][3]);
      pk.z = pkbf(vcur[r][4], vcur[r][5]);
      pk.w = pkbf(vcur[r][6], vcur[r][7]);
      *(uint4*)(Bh + lB * 72 + oct * 8) = pk;
    }
    float vnext[RIT][8];
    if (c0 + 1 < nch) gather(c0 + 1, vnext);
    const int a0 = (c0 << 6) + quad * 8;
    short8v ah0 = *(const short8v*)(arowH + a0);
    short8v al0 = *(const short8v*)(arowL + a0);
    short8v ah1 = *(const short8v*)(arowH + a0 + 32);
    short8v al1 = *(const short8v*)(arowL + a0 + 32);
    __syncthreads();
#pragma unroll
    for (int t = 0; t < T; ++t) {
      const int l = m0 + 16 * t;
      short8v b0 = *(const short8v*)(Bh + l * 72 + quad * 8);
      short8v b1 = *(const short8v*)(Bh + l * 72 + 32 + quad * 8);
      acc[t] = __builtin_amdgcn_mfma_f32_16x16x32_bf16(ah0, b0, acc[t], 0, 0, 0);
      acc[t] = __builtin_amdgcn_mfma_f32_16x16x32_bf16(al0, b0, acc[t], 0, 0, 0);
      acc[t] = __builtin_amdgcn_mfma_f32_16x16x32_bf16(ah1, b1, acc[t], 0, 0, 0);
      acc[t] = __builtin_amdgcn_mfma_f32_16x16x32_bf16(al1, b1, acc[t], 0, 0, 0);
    }
    __syncthreads();
    if (c0 + 1 < nch) {
#pragma unroll
      for (int r = 0; r < RIT; ++r)
#pragma unroll
        for (int j = 0; j < 8; ++j) vcur[r][j] = vnext[r][j];
    }
  }

#pragma unroll
  for (int reg = 0; reg < 4; ++reg) {
    const int co = coBase + quad * 4 + reg;
    if (co < Co) {
      float* yp = Y + (((size_t)b * Co + co) * Hout + s) * L + l0;
#pragma unroll
      for (int t = 0; t < T; ++t) yp[m0 + 16 * t] = acc[t][reg];
    }
  }
  if (stOut) {
#pragma unroll
    for (int reg = 0; reg < 4; ++reg) {
      float s1 = 0.f, s2 = 0.f;
#pragma unroll
      for (int t = 0; t < T; ++t) {
        s1 += acc[t][reg];
        s2 += acc[t][reg] * acc[t][reg];
      }
#pragma unroll
      for (int off = 1; off < 16; off <<= 1) {
        s1 += __shfl_xor(s1, off);
        s2 += __shfl_xor(s2, off);
      }
      const int co = coBase + quad * 4 + reg;
      if (m0 == 0 && co < Co) {
        atomicAdd(&stOut[co], s1);
        atomicAdd(&stOut[512 + co], s2);
      }
    }
  }
}

// ---------------------------------------------------------------------------
// gg_tail: no-LDS GConvGG for small stages (input pre-activated)
// ---------------------------------------------------------------------------
template <int NK, int L, int COSUB>
__global__ __launch_bounds__(256) void gg_tail_kernel(
    const float* __restrict__ X, const float* __restrict__ W,
    float* __restrict__ Y, float* __restrict__ stOut, int Ci, int Co,
    int Hin) {
  const int l = threadIdx.x % L;
  const int cs = threadIdx.x / L;
  const int co = blockIdx.x * COSUB + cs;
  const int s = blockIdx.y;
  const int b = blockIdx.z;
  const int Hout = Hin - NK + 1;

  float acc[NK];
#pragma unroll
  for (int i = 0; i < NK; ++i) acc[i] = 0.f;

  const float* wbase = W + (size_t)co * Ci * NK * 3;
  const float* xbase = X + ((size_t)b * Ci * Hin + s) * L;

  for (int ci = 0; ci < Ci; ++ci) {
    const float* wp = wbase + ci * (NK * 3);
    const float* xr = xbase + ci * (Hin * L);
#pragma unroll
    for (int i = 0; i < NK; ++i) {
      const int d = 1 << (s + i);
      const float* row = xr + i * L;
      float xm = (l >= d) ? row[l - d] : 0.f;
      float xc = row[l];
      float xp = (l + d < L) ? row[l + d] : 0.f;
      acc[i] = fmaf(wp[3 * i], xm,
                    fmaf(wp[3 * i + 1], xc, fmaf(wp[3 * i + 2], xp, acc[i])));
    }
  }
  float out = 0.f;
#pragma unroll
  for (int i = 0; i < NK; ++i) {
    float invd = __uint_as_float((unsigned)(127 - (s + i)) << 23);
    out = fmaf(acc[i], invd, out);
  }
  Y[(((size_t)b * Co + co) * Hout + s) * L + l] = out;

  float s1 = out, s2 = out * out;
  constexpr int RED = (L < 64) ? L : 64;
#pragma unroll
  for (int off = RED / 2; off > 0; off >>= 1) {
    s1 += __shfl_xor(s1, off);
    s2 += __shfl_xor(s2, off);
  }
  if ((threadIdx.x & (RED - 1)) == 0) {
    atomicAdd(&stOut[co], s1);
    atomicAdd(&stOut[512 + co], s2);
  }
}

// ---------------------------------------------------------------------------
// gg_tail_split: K-split tail for gg9/gg10 (Hout=1, s=0); atomic accumulate.
// ---------------------------------------------------------------------------
template <int NK, int L, int COSUB>
__global__ __launch_bounds__(256) void gg_tail_split_kernel(
    const float* __restrict__ X, const float* __restrict__ W,
    float* __restrict__ Y, int Ci, int Co, int Hin, int ciPer) {
  const int l = threadIdx.x % L;
  const int cs = threadIdx.x / L;
  const int co = blockIdx.x * COSUB + cs;
  const int b = blockIdx.z;
  const int ciBeg = blockIdx.y * ciPer;
  const int ciEnd = min(Ci, ciBeg + ciPer);

  float acc[NK];
#pragma unroll
  for (int i = 0; i < NK; ++i) acc[i] = 0.f;

  const float* wbase = W + (size_t)co * Ci * NK * 3;
  const float* xbase = X + (size_t)b * Ci * Hin * L;

  for (int ci = ciBeg; ci < ciEnd; ++ci) {
    const float* wp = wbase + ci * (NK * 3);
    const float* xr = xbase + ci * (Hin * L);
#pragma unroll
    for (int i = 0; i < NK; ++i) {
      const int d = 1 << i;
      const float* row = xr + i * L;
      float xm = (l >= d) ? row[l - d] : 0.f;
      float xc = row[l];
      float xp = (l + d < L) ? row[l + d] : 0.f;
      acc[i] = fmaf(wp[3 * i], xm,
                    fmaf(wp[3 * i + 1], xc, fmaf(wp[3 * i + 2], xp, acc[i])));
    }
  }
  float out = 0.f;
#pragma unroll
  for (int i = 0; i < NK; ++i) {
    float invd = __uint_as_float((unsigned)(127 - i) << 23);
    out = fmaf(acc[i], invd, out);
  }
  atomicAdd(&Y[((size_t)b * Co + co) * L + l], out);
}

// ---------------------------------------------------------------------------
// Final: bn10+relu, mean over L, classifier
// ---------------------------------------------------------------------------
__global__ __launch_bounds__(256) void final_kernel(
    const float* __restrict__ Y, const float* __restrict__ st,
    const float* __restrict__ g, const float* __restrict__ bb,
    const float* __restrict__ w11, float* __restrict__ out) {
  const int b = blockIdx.x;
  const int tid = threadIdx.x;
  __shared__ float tch[408];
  for (int c = tid; c < 408; c += 256) {
    float m = st[c] * (1.f / 256.f);
    float v = st[512 + c] * (1.f / 256.f) - m * m;
    float sc = g[c] * rsqrtf(v + EPSBN);
    float bi = bb[c] - m * sc;
    const float* p = Y + ((size_t)b * 408 + c) * 32;
    float ssum = 0.f;
#pragma unroll
    for (int l = 0; l < 32; ++l) ssum += fmaxf(p[l] * sc + bi, 0.f);
    tch[c] = ssum * (1.f / 32.f);
  }
  __syncthreads();
  if (tid < 10) {
    float ssum = 0.f;
    for (int c = 0; c < 408; ++c) ssum += w11[tid * 408 + c] * tch[c];
    out[b * 10 + tid] = ssum;
  }
}

// ---------------------------------------------------------------------------
extern "C" void kernel_launch(void* const* d_in, const int* in_sizes, int n_in,
                              void* d_out, int out_size, void* d_ws,
                              size_t ws_size, hipStream_t stream) {
  const float* x = (const float*)d_in[0];
  const float* w1 = (const float*)d_in[1];
  const float* w2 = (const float*)d_in[2];
  const float* w3 = (const float*)d_in[3];
  const float* w4 = (const float*)d_in[4];
  const float* w5 = (const float*)d_in[5];
  const float* w6 = (const float*)d_in[6];
  const float* w7 = (const float*)d_in[7];
  const float* w8 = (const float*)d_in[8];
  const float* w9 = (const float*)d_in[9];
  const float* w10 = (const float*)d_in[10];
  const float* w11 = (const float*)d_in[11];
  const float* gg[11];
  const float* bbv[11];
  for (int i = 1; i <= 10; ++i) {
    gg[i] = (const float*)d_in[12 + 2 * (i - 1)];
    bbv[i] = (const float*)d_in[12 + 2 * (i - 1) + 1];
  }

  float* ws = (float*)d_ws;
  const size_t AR0 = 0;
  const size_t AR1 = 30081024;
  const size_t STATS = 37601280;
  float* y1 = ws + AR0;
  float* xpad = ws + AR1;                     // 456704 floats
  short* apk1 = (short*)(ws + AR1 + 460800);  // 9*2*64*96 = 110592 shorts
  float* z1 = ws + AR1;                       // overwrites xpad/apk1 later (ok)
  float* y2 = ws + AR0;
  float* y3 = ws + AR0 + 5849088;
  float* a3act = ws + AR1;
  float* z3 = ws + AR1;
  float* y4 = ws + AR0;
  float* y5 = ws + AR0 + 2088960;
  float* a5act = ws + AR1 + 1500000;
  float* z5 = ws + AR1;
  float* a6 = ws + AR1 + 522240;
  float* a7 = ws + AR1 + 1148928;
  float* z8 = ws + AR1;
  float* a9 = ws + AR1 + 1775616;
  float* y6 = ws + AR0;
  float* y7 = ws + AR0 + 626688;
  float* y8 = ws + AR0 + 1253376;
  float* y9 = ws + AR0;
  float* y10 = ws + AR0 + 104448;
  short* apk2 = (short*)(ws + 12000000);
  short* apk3 = apk2 + 7 * 2 * 64 * 512;
  short* apk4 = apk3 + 7 * 2 * 64 * 192;
  short* apk5 = apk4 + 5 * 2 * 128 * 512;
  float* st[11];
  for (int i = 1; i <= 10; ++i) st[i] = ws + STATS + (size_t)(i - 1) * 1024;

  hipMemsetAsync((void*)(ws + STATS), 0, 10 * 1024 * sizeof(float), stream);

  // ---- pad x, pack w1, MFMA lift (+ separate stats1 pass)
  pad_x_kernel<<<(8 * PROW + 255) / 256, 256, 0, stream>>>(x, xpad);
  pack_w1_kernel<<<(9 * 64 * 96 + 255) / 256, 256, 0, stream>>>(w1, apk1);
  lift_mfma_kernel<<<dim3(512, 9, 8), 256, 0, stream>>>(xpad, apk1, y1);
  stats_kernel<<<dim3(51, 8), 256, 0, stream>>>(y1, st[1], 51, 9 * 8192);
  {
    unsigned int tot = 8u * 51 * 9 * 2048;
    bnrelu_pool_kernel<<<(tot + 255) / 256, 256, 0, stream>>>(
        y1, st[1], gg[1], bbv[1], z1, 51, 9, 8192, 1.f / 589824.f, tot);
  }
  // ---- per-s weight packs (y1 dead; packs region free)
  pack_w2_kernel<<<(7 * 64 * 512 + 255) / 256, 256, 0, stream>>>(
      w2, apk2, 51, 459, 512, 64, 7, 9);
  pack_w2_kernel<<<(7 * 64 * 192 + 255) / 256, 256, 0, stream>>>(
      w3, apk3, 51, 153, 192, 64, 7, 3);
  pack_w2_kernel<<<(5 * 128 * 512 + 255) / 256, 256, 0, stream>>>(
      w4, apk4, 102, 459, 512, 128, 5, 9);
  pack_w2_kernel<<<(5 * 128 * 320 + 255) / 256, 256, 0, stream>>>(
      w5, apk5, 102, 306, 320, 128, 5, 3);
  // ---- gg2: 51->51, H 9->7, L=2048
  gg_mfma4_kernel<3, 64><<<dim3(32, 7, 8), 256, 0, stream>>>(
      z1, apk2, y2, st[2], 51, 51, 9, 2048, 32, 459, 512, 64);
  {
    unsigned int tot = 8u * 51 * 7 * 2048;
    bnrelu_kernel<<<(tot + 255) / 256, 256, 0, stream>>>(
        y2, st[2], gg[2], bbv[2], a3act, 51, 7 * 2048, 1.f / 114688.f, tot);
  }
  // ---- gg3: 51->51, H7, L=2048
  gg_mfma4_kernel<1, 64><<<dim3(32, 7, 8), 256, 0, stream>>>(
      a3act, apk3, y3, st[3], 51, 51, 7, 2048, 32, 153, 192, 64);
  {
    unsigned int tot = 8u * 51 * 7 * 512;
    bnrelu_pool_kernel<<<(tot + 255) / 256, 256, 0, stream>>>(
        y3, st[3], gg[3], bbv[3], z3, 51, 7, 2048, 1.f / 114688.f, tot);
  }
  // ---- gg4: 51->102, H 7->5, L=512
  gg_mfma4_kernel<3, 32><<<dim3(32, 5, 8), 256, 0, stream>>>(
      z3, apk4, y4, st[4], 51, 102, 7, 512, 16, 459, 512, 128);
  {
    unsigned int tot = 8u * 102 * 5 * 512;
    bnrelu_kernel<<<(tot + 255) / 256, 256, 0, stream>>>(
        y4, st[4], gg[4], bbv[4], a5act, 102, 5 * 512, 1.f / 20480.f, tot);
  }
  // ---- gg5: 102->102, H5, L=512
  gg_mfma4_kernel<1, 32><<<dim3(32, 5, 8), 256, 0, stream>>>(
      a5act, apk5, y5, st[5], 102, 102, 5, 512, 16, 306, 320, 128);
  {
    unsigned int tot = 8u * 102 * 5 * 128;
    bnrelu_pool_kernel<<<(tot + 255) / 256, 256, 0, stream>>>(
        y5, st[5], gg[5], bbv[5], z5, 102, 5, 512, 1.f / 20480.f, tot);
  }
  // ---- gg6: 102->204, H 5->3, L=128
  gg_tail_kernel<3, 128, 2><<<dim3(102, 3, 8), 256, 0, stream>>>(
      z5, w6, y6, st[6], 102, 204, 5);
  {
    unsigned int tot = 8u * 204 * 3 * 128;
    bnrelu_kernel<<<(tot + 255) / 256, 256, 0, stream>>>(
        y6, st[6], gg[6], bbv[6], a6, 204, 3 * 128, 1.f / 3072.f, tot);
  }
  // ---- gg7: 204->204, H3, L=128
  gg_tail_kernel<1, 128, 2><<<dim3(102, 3, 8), 256, 0, stream>>>(
      a6, w7, y7, st[7], 204, 204, 3);
  {
    unsigned int tot = 8u * 204 * 3 * 128;
    bnrelu_kernel<<<(tot + 255) / 256, 256, 0, stream>>>(
        y7, st[7], gg[7], bbv[7], a7, 204, 3 * 128, 1.f / 3072.f, tot);
  }
  // ---- gg8: 204->204, H3, L=128
  gg_tail_kernel<1, 128, 2><<<dim3(102, 3, 8), 256, 0, stream>>>(
      a7, w8, y8, st[8], 204, 204, 3);
  {
    unsigned int tot = 8u * 204 * 3 * 32;
    bnrelu_pool_kernel<<<(tot + 255) / 256, 256, 0, stream>>>(
        y8, st[8], gg[8], bbv[8], z8, 204, 3, 128, 1.f / 3072.f, tot);
  }
  // ---- gg9: 204->408, H 3->1, L=32 (K-split x4)
  hipMemsetAsync((void*)y9, 0, 2 * 104448 * sizeof(float), stream);
  gg_tail_split_kernel<3, 32, 8><<<dim3(51, 4, 8), 256, 0, stream>>>(
      z8, w9, y9, 204, 408, 3, 51);
  stats_kernel<<<dim3(408, 8), 256, 0, stream>>>(y9, st[9], 408, 32);
  {
    unsigned int tot = 8u * 408 * 32;
    bnrelu_kernel<<<(tot + 255) / 256, 256, 0, stream>>>(
        y9, st[9], gg[9], bbv[9], a9, 408, 32, 1.f / 256.f, tot);
  }
  // ---- gg10: 408->408, H1, L=32 (K-split x4)
  gg_tail_split_kernel<1, 32, 8><<<dim3(51, 4, 8), 256, 0, stream>>>(
      a9, w10, y10, 408, 408, 1, 102);
  stats_kernel<<<dim3(408, 8), 256, 0, stream>>>(y10, st[10], 408, 32);
  // ---- final
  final_kernel<<<dim3(8), 256, 0, stream>>>(y10, st[10], gg[10], bbv[10], w11,
                                            (float*)d_out);
}

// Round 13
// 1371.720 us; speedup vs baseline: 1.6276x; 1.0792x over previous
//
#include <hip/hip_runtime.h>
#include <hip/hip_bf16.h>

#define EPSBN 2e-5f

typedef __attribute__((ext_vector_type(8))) short short8v;
typedef __attribute__((ext_vector_type(4))) float f32x4;

__device__ inline unsigned short f2bf(float f) {
  unsigned u = __float_as_uint(f);
  unsigned r = (u + 0x7FFFu + ((u >> 16) & 1u)) >> 16;
  return (unsigned short)r;
}
__device__ inline float bf2f(unsigned short h) {
  return __uint_as_float(((unsigned)h) << 16);
}

// ---------------------------------------------------------------------------
// Padded x staging
// ---------------------------------------------------------------------------
constexpr int XPADL = 9984;
constexpr int XPADR = 14336;
constexpr int PROW = XPADL + 32768 + XPADR;  // 57088

__global__ __launch_bounds__(256) void pad_x_kernel(const float* __restrict__ x,
                                                    float* __restrict__ xp) {
  int i = blockIdx.x * 256 + threadIdx.x;
  if (i >= 8 * PROW) return;
  int b = i / PROW;
  int pos = i - b * PROW - XPADL;
  xp[i] = (pos >= 0 && pos < 32768) ? x[b * 32768 + pos] : 0.f;
}

// ---------------------------------------------------------------------------
// Pack w1 [51][79] -> per-s split bf16 (1/2^s folded), [s][hi/lo][64][96]
// ---------------------------------------------------------------------------
__global__ __launch_bounds__(256) void pack_w1_kernel(
    const float* __restrict__ W, short* __restrict__ A) {
  int idx = blockIdx.x * 256 + threadIdx.x;
  if (idx >= 9 * 64 * 96) return;
  int s = idx / (64 * 96);
  int rem = idx - s * 64 * 96;
  int co = rem / 96;
  int k = rem - co * 96;
  float v = 0.f;
  if (co < 51 && k < 79)
    v = W[co * 79 + k] * __uint_as_float((unsigned)(127 - s) << 23);
  unsigned short hi = f2bf(v);
  unsigned short lo = f2bf(v - bf2f(hi));
  A[(size_t)s * 2 * 64 * 96 + co * 96 + k] = (short)hi;
  A[(size_t)s * 2 * 64 * 96 + 64 * 96 + co * 96 + k] = (short)lo;
}

// ---------------------------------------------------------------------------
// lift_mfma: lift conv K=79 as bf16 MFMA GEMM + fused pool4 (R12, unchanged)
// ---------------------------------------------------------------------------
__global__ __launch_bounds__(256) void lift_mfma_kernel(
    const float* __restrict__ xp, const short* __restrict__ Apk1,
    float* __restrict__ y1) {
  constexpr int P = 104;
  const int lc = blockIdx.x;
  const int s = blockIdx.y;
  const int b = blockIdx.z;
  const int d = 1 << s;
  const int l0 = lc * 64;
  const int tid = threadIdx.x;
  const int lane = tid & 63;
  const int quad = lane >> 4;
  const int n0 = lane & 15;
  const int wv = tid >> 6;
  const int coBase = wv * 16;

  __shared__ __align__(16) short Bh[64 * P];
  __shared__ __align__(16) short Bl[64 * P];

  const float* xrow = xp + b * PROW + XPADL;

  const int nB = tid & 63;
  const int og = tid >> 6;
#pragma unroll
  for (int r = 0; r < 3; ++r) {
    const int oct = og + 4 * r;
    const int kb = oct * 8;
    float v[8];
#pragma unroll
    for (int j = 0; j < 8; ++j) v[j] = xrow[l0 + nB + (kb + j - 39) * d];
    unsigned h[8], lo[8];
#pragma unroll
    for (int j = 0; j < 8; ++j) {
      unsigned u = __float_as_uint(v[j]);
      h[j] = u >> 16;
      float lof = v[j] - __uint_as_float(u & 0xffff0000u);
      lo[j] = __float_as_uint(lof) >> 16;
    }
    uint4 ph, pl;
    ph.x = h[0] | (h[1] << 16);
    ph.y = h[2] | (h[3] << 16);
    ph.z = h[4] | (h[5] << 16);
    ph.w = h[6] | (h[7] << 16);
    pl.x = lo[0] | (lo[1] << 16);
    pl.y = lo[2] | (lo[3] << 16);
    pl.z = lo[4] | (lo[5] << 16);
    pl.w = lo[6] | (lo[7] << 16);
    *(uint4*)(Bh + nB * P + kb) = ph;
    *(uint4*)(Bl + nB * P + kb) = pl;
  }

  const short* ApkS = Apk1 + (size_t)s * 2 * 64 * 96;
  const short* arowH = ApkS + (coBase + n0) * 96;
  const short* arowL = arowH + 64 * 96;

  __syncthreads();

  f32x4 acc[4];
#pragma unroll
  for (int t = 0; t < 4; ++t) acc[t] = (f32x4){0.f, 0.f, 0.f, 0.f};

#pragma unroll
  for (int ks = 0; ks < 3; ++ks) {
    short8v ah = *(const short8v*)(arowH + ks * 32 + quad * 8);
    short8v al = *(const short8v*)(arowL + ks * 32 + quad * 8);
#pragma unroll
    for (int t = 0; t < 4; ++t) {
      const int n = n0 + 16 * t;
      short8v bh = *(const short8v*)(Bh + n * P + ks * 32 + quad * 8);
      short8v bl = *(const short8v*)(Bl + n * P + ks * 32 + quad * 8);
      acc[t] = __builtin_amdgcn_mfma_f32_16x16x32_bf16(ah, bh, acc[t], 0, 0, 0);
      acc[t] = __builtin_amdgcn_mfma_f32_16x16x32_bf16(ah, bl, acc[t], 0, 0, 0);
      acc[t] = __builtin_amdgcn_mfma_f32_16x16x32_bf16(al, bh, acc[t], 0, 0, 0);
    }
  }

#pragma unroll
  for (int reg = 0; reg < 4; ++reg) {
    const int co = coBase + quad * 4 + reg;
#pragma unroll
    for (int t = 0; t < 4; ++t) {
      float u = acc[t][reg];
      u = fmaxf(u, __shfl_xor(u, 1));
      u = fmaxf(u, __shfl_xor(u, 2));
      if ((n0 & 3) == 0 && co < 51) {
        const int l1 = (l0 >> 2) + t * 4 + (n0 >> 2);
        y1[(((size_t)b * 51 + co) * 9 + s) * 8192 + l1] = u;
      }
    }
  }
}

// ---------------------------------------------------------------------------
// Per-channel sum/sumsq over [B,C,HL], HL split NS ways; grid (C,B,NS)
// ---------------------------------------------------------------------------
__global__ __launch_bounds__(256) void stats_kernel(
    const float* __restrict__ Y, float* __restrict__ st, int C, int HL,
    int NS) {
  const int c = blockIdx.x, b = blockIdx.y, z = blockIdx.z;
  const int slice = HL / NS;
  const float* p = Y + ((size_t)b * C + c) * HL + (size_t)z * slice;
  float s = 0.f, q = 0.f;
  for (int i = threadIdx.x; i < slice; i += 256) {
    float v = p[i];
    s += v;
    q += v * v;
  }
#pragma unroll
  for (int off = 32; off > 0; off >>= 1) {
    s += __shfl_down(s, off, 64);
    q += __shfl_down(q, off, 64);
  }
  __shared__ float ls[4], lq[4];
  const int wid = threadIdx.x >> 6, lane = threadIdx.x & 63;
  if (lane == 0) { ls[wid] = s; lq[wid] = q; }
  __syncthreads();
  if (threadIdx.x == 0) {
    atomicAdd(&st[c], ls[0] + ls[1] + ls[2] + ls[3]);
    atomicAdd(&st[512 + c], lq[0] + lq[1] + lq[2] + lq[3]);
  }
}

// ---------------------------------------------------------------------------
// BN(train)+ReLU+pool4, fp32 out
// ---------------------------------------------------------------------------
__global__ __launch_bounds__(256) void bnrelu_pool_kernel(
    const float* __restrict__ Y, const float* __restrict__ st,
    const float* __restrict__ g, const float* __restrict__ bb,
    float* __restrict__ Z, int C, int H, int Lin, float invN,
    unsigned int total) {
  unsigned int idx = blockIdx.x * 256u + threadIdx.x;
  if (idx >= total) return;
  const unsigned int Lo = (unsigned int)(Lin >> 2);
  unsigned int lo = idx % Lo;
  unsigned int r1 = idx / Lo;
  unsigned int h = r1 % (unsigned int)H;
  unsigned int r2 = r1 / (unsigned int)H;
  unsigned int c = r2 % (unsigned int)C;
  unsigned int b = r2 / (unsigned int)C;
  float m = st[c] * invN;
  float v = st[512 + c] * invN - m * m;
  float sc = g[c] * rsqrtf(v + EPSBN);
  float bi = bb[c] - m * sc;
  const float* p = Y + (((size_t)b * C + c) * H + h) * Lin + 4u * lo;
  float a0 = p[0] * sc + bi, a1 = p[1] * sc + bi;
  float a2 = p[2] * sc + bi, a3 = p[3] * sc + bi;
  float r = fmaxf(fmaxf(a0, a1), fmaxf(a2, a3));
  Z[idx] = fmaxf(r, 0.f);
}

// ---- same, bf16 out
__global__ __launch_bounds__(256) void bnrelu_pool_bf16_kernel(
    const float* __restrict__ Y, const float* __restrict__ st,
    const float* __restrict__ g, const float* __restrict__ bb,
    unsigned short* __restrict__ Z, int C, int H, int Lin, float invN,
    unsigned int total) {
  unsigned int idx = blockIdx.x * 256u + threadIdx.x;
  if (idx >= total) return;
  const unsigned int Lo = (unsigned int)(Lin >> 2);
  unsigned int lo = idx % Lo;
  unsigned int r1 = idx / Lo;
  unsigned int h = r1 % (unsigned int)H;
  unsigned int r2 = r1 / (unsigned int)H;
  unsigned int c = r2 % (unsigned int)C;
  unsigned int b = r2 / (unsigned int)C;
  float m = st[c] * invN;
  float v = st[512 + c] * invN - m * m;
  float sc = g[c] * rsqrtf(v + EPSBN);
  float bi = bb[c] - m * sc;
  const float* p = Y + (((size_t)b * C + c) * H + h) * Lin + 4u * lo;
  float a0 = p[0] * sc + bi, a1 = p[1] * sc + bi;
  float a2 = p[2] * sc + bi, a3 = p[3] * sc + bi;
  float r = fmaxf(fmaxf(a0, a1), fmaxf(a2, a3));
  Z[idx] = f2bf(fmaxf(r, 0.f));
}

// ---------------------------------------------------------------------------
// BN(train)+ReLU elementwise, fp32 / bf16 out
// ---------------------------------------------------------------------------
__global__ __launch_bounds__(256) void bnrelu_kernel(
    const float* __restrict__ Y, const float* __restrict__ st,
    const float* __restrict__ g, const float* __restrict__ bb,
    float* __restrict__ A, int C, int HL, float invN, unsigned int total) {
  unsigned int idx = blockIdx.x * 256u + threadIdx.x;
  if (idx >= total) return;
  unsigned int c = (idx / (unsigned int)HL) % (unsigned int)C;
  float m = st[c] * invN;
  float v = st[512 + c] * invN - m * m;
  float sc = g[c] * rsqrtf(v + EPSBN);
  float bi = bb[c] - m * sc;
  A[idx] = fmaxf(fmaf(Y[idx], sc, bi), 0.f);
}

__global__ __launch_bounds__(256) void bnrelu_bf16_kernel(
    const float* __restrict__ Y, const float* __restrict__ st,
    const float* __restrict__ g, const float* __restrict__ bb,
    unsigned short* __restrict__ A, int C, int HL, float invN,
    unsigned int total) {
  unsigned int idx = blockIdx.x * 256u + threadIdx.x;
  if (idx >= total) return;
  unsigned int c = (idx / (unsigned int)HL) % (unsigned int)C;
  float m = st[c] * invN;
  float v = st[512 + c] * invN - m * m;
  float sc = g[c] * rsqrtf(v + EPSBN);
  float bi = bb[c] - m * sc;
  A[idx] = f2bf(fmaxf(fmaf(Y[idx], sc, bi), 0.f));
}

// ---------------------------------------------------------------------------
// Pack fp32 weights -> per-s split bf16 packs with 2^-(s+i) folded.
// ---------------------------------------------------------------------------
__global__ __launch_bounds__(256) void pack_w2_kernel(
    const float* __restrict__ W, short* __restrict__ A, int Co, int KTOT,
    int KPAD, int COPAD, int NS, int nk3) {
  int idx = blockIdx.x * 256 + threadIdx.x;
  const int CK = COPAD * KPAD;
  if (idx >= NS * CK) return;
  int s = idx / CK;
  int rem = idx - s * CK;
  int co = rem / KPAD;
  int kk = rem - co * KPAD;
  float v = 0.f;
  if (co < Co && kk < KTOT) {
    int i = (kk % nk3) / 3;
    float scale = __uint_as_float((unsigned)(127 - (s + i)) << 23);
    v = W[co * KTOT + kk] * scale;
  }
  unsigned short hi = f2bf(v);
  unsigned short lo = f2bf(v - bf2f(hi));
  A[(size_t)s * 2 * CK + co * KPAD + kk] = (short)hi;
  A[(size_t)s * 2 * CK + CK + co * KPAD + kk] = (short)lo;
}

// ---------------------------------------------------------------------------
// gg_mfma5: bf16-input, depth-2 register-prefetch MFMA GConvGG.
// X is PRE-ACTIVATED bf16 (ushort) -> gathers load 2B, no cvt in-loop,
// half-size tensors are L2-resident. Ring of packed uint4 chunks covers
// ~2 chunk-iterations of load latency. Numerics bit-identical to R12
// (B values were RNE-bf16 there too).
// ---------------------------------------------------------------------------
template <int NKv, int LT>
__global__ __launch_bounds__(256) void gg_mfma5_kernel(
    const unsigned short* __restrict__ X, const short* __restrict__ Apk,
    float* __restrict__ Y, float* __restrict__ stOut, int Ci, int Co, int Hin,
    int L, int nL, int KTOT, int KPAD, int COPAD) {
  constexpr int T = LT / 16;
  constexpr int KO = 256 / LT;
  constexpr int RIT = 8 / KO;

  const int bx = blockIdx.x;
  const int lc = bx % nL;
  const int cog = bx / nL;
  const int s = blockIdx.y;
  const int b = blockIdx.z;
  const int Hout = Hin - NKv + 1;
  const int l0 = lc * LT;
  const int tid = threadIdx.x;
  const int lane = tid & 63;
  const int quad = lane >> 4;
  const int m0 = lane & 15;
  const int wv = tid >> 6;
  const int coBase = cog * 64 + wv * 16;

  __shared__ __align__(16) short Bh[LT * 72];
  __shared__ int roT[512];
  __shared__ int shT[512];

  for (int kk = tid; kk < KPAD; kk += 256) {
    int ro = 0, sh = -(1 << 30);
    if (kk < KTOT) {
      int ci = kk / (3 * NKv);
      int rem = kk - ci * (3 * NKv);
      int i = rem / 3;
      int k = rem - 3 * i;
      ro = (ci * Hin + s + i) * L;
      sh = (k - 1) * (1 << (s + i));
    }
    roT[kk] = ro;
    shT[kk] = sh;
  }
  __syncthreads();

  f32x4 acc[T];
#pragma unroll
  for (int t = 0; t < T; ++t) acc[t] = (f32x4){0.f, 0.f, 0.f, 0.f};

  const short* ApkS = Apk + (size_t)s * 2 * COPAD * KPAD;
  const short* arowH = ApkS + (size_t)(coBase + m0) * KPAD;
  const short* arowL = arowH + (size_t)COPAD * KPAD;
  const unsigned short* Xb = X + (size_t)b * Ci * Hin * L;

  const int lB = tid & (LT - 1);
  const int oc0 = tid / LT;
  const int nch = (KTOT + 63) >> 6;

  uint4 v0[RIT], v1[RIT], v2[RIT];
  auto gather = [&](int c0, uint4 (&pk)[RIT]) {
#pragma unroll
    for (int r = 0; r < RIT; ++r) {
      const int oct = oc0 + KO * r;
      const int kkb = (c0 << 6) + oct * 8;
      unsigned w[8];
#pragma unroll
      for (int j = 0; j < 8; ++j) {
        const int kk = kkb + j;
        const int pos = l0 + lB + shT[kk];
        const int posc = min(max(pos, 0), L - 1);
        unsigned u = (unsigned)Xb[roT[kk] + posc];
        w[j] = ((unsigned)pos < (unsigned)L) ? u : 0u;
      }
      pk[r].x = w[0] | (w[1] << 16);
      pk[r].y = w[2] | (w[3] << 16);
      pk[r].z = w[4] | (w[5] << 16);
      pk[r].w = w[6] | (w[7] << 16);
    }
  };

  gather(0, v0);
  if (nch > 1) gather(1, v1);
  for (int c0 = 0; c0 < nch; ++c0) {
#pragma unroll
    for (int r = 0; r < RIT; ++r)
      *(uint4*)(Bh + lB * 72 + (oc0 + KO * r) * 8) = v0[r];
    if (c0 + 2 < nch) gather(c0 + 2, v2);
    const int a0 = (c0 << 6) + quad * 8;
    short8v ah0 = *(const short8v*)(arowH + a0);
    short8v al0 = *(const short8v*)(arowL + a0);
    short8v ah1 = *(const short8v*)(arowH + a0 + 32);
    short8v al1 = *(const short8v*)(arowL + a0 + 32);
    __syncthreads();
#pragma unroll
    for (int t = 0; t < T; ++t) {
      const int l = m0 + 16 * t;
      short8v b0 = *(const short8v*)(Bh + l * 72 + quad * 8);
      short8v b1 = *(const short8v*)(Bh + l * 72 + 32 + quad * 8);
      acc[t] = __builtin_amdgcn_mfma_f32_16x16x32_bf16(ah0, b0, acc[t], 0, 0, 0);
      acc[t] = __builtin_amdgcn_mfma_f32_16x16x32_bf16(al0, b0, acc[t], 0, 0, 0);
      acc[t] = __builtin_amdgcn_mfma_f32_16x16x32_bf16(ah1, b1, acc[t], 0, 0, 0);
      acc[t] = __builtin_amdgcn_mfma_f32_16x16x32_bf16(al1, b1, acc[t], 0, 0, 0);
    }
    __syncthreads();
#pragma unroll
    for (int r = 0; r < RIT; ++r) {
      v0[r] = v1[r];
      v1[r] = v2[r];
    }
  }

#pragma unroll
  for (int reg = 0; reg < 4; ++reg) {
    const int co = coBase + quad * 4 + reg;
    if (co < Co) {
      float* yp = Y + (((size_t)b * Co + co) * Hout + s) * L + l0;
#pragma unroll
      for (int t = 0; t < T; ++t) yp[m0 + 16 * t] = acc[t][reg];
    }
  }
  if (stOut) {
#pragma unroll
    for (int reg = 0; reg < 4; ++reg) {
      float s1 = 0.f, s2 = 0.f;
#pragma unroll
      for (int t = 0; t < T; ++t) {
        s1 += acc[t][reg];
        s2 += acc[t][reg] * acc[t][reg];
      }
#pragma unroll
      for (int off = 1; off < 16; off <<= 1) {
        s1 += __shfl_xor(s1, off);
        s2 += __shfl_xor(s2, off);
      }
      const int co = coBase + quad * 4 + reg;
      if (m0 == 0 && co < Co) {
        atomicAdd(&stOut[co], s1);
        atomicAdd(&stOut[512 + co], s2);
      }
    }
  }
}

// ---------------------------------------------------------------------------
// gg_tail2: K-split no-LDS GConvGG (input pre-activated fp32).
// grid (Co/COSUB, Hout*NSPLIT, B); atomicAdd into pre-zeroed Y; stats via
// separate stats pass.
// ---------------------------------------------------------------------------
template <int NK, int L, int COSUB>
__global__ __launch_bounds__(256) void gg_tail2_kernel(
    const float* __restrict__ X, const float* __restrict__ W,
    float* __restrict__ Y, int Ci, int Co, int Hin, int NSPLIT, int ciPer) {
  const int l = threadIdx.x % L;
  const int cs = threadIdx.x / L;
  const int co = blockIdx.x * COSUB + cs;
  const int s = blockIdx.y / NSPLIT;
  const int seg = blockIdx.y % NSPLIT;
  const int b = blockIdx.z;
  const int Hout = Hin - NK + 1;
  const int ciBeg = seg * ciPer;
  const int ciEnd = min(Ci, ciBeg + ciPer);

  float acc[NK];
#pragma unroll
  for (int i = 0; i < NK; ++i) acc[i] = 0.f;

  const float* wbase = W + (size_t)co * Ci * NK * 3;
  const float* xbase = X + ((size_t)b * Ci * Hin + s) * L;

  for (int ci = ciBeg; ci < ciEnd; ++ci) {
    const float* wp = wbase + ci * (NK * 3);
    const float* xr = xbase + ci * (Hin * L);
#pragma unroll
    for (int i = 0; i < NK; ++i) {
      const int d = 1 << (s + i);
      const float* row = xr + i * L;
      float xm = (l >= d) ? row[l - d] : 0.f;
      float xc = row[l];
      float xp = (l + d < L) ? row[l + d] : 0.f;
      acc[i] = fmaf(wp[3 * i], xm,
                    fmaf(wp[3 * i + 1], xc, fmaf(wp[3 * i + 2], xp, acc[i])));
    }
  }
  float out = 0.f;
#pragma unroll
  for (int i = 0; i < NK; ++i) {
    float invd = __uint_as_float((unsigned)(127 - (s + i)) << 23);
    out = fmaf(acc[i], invd, out);
  }
  atomicAdd(&Y[(((size_t)b * Co + co) * Hout + s) * L + l], out);
}

// ---------------------------------------------------------------------------
// Final: bn10+relu, mean over L, classifier
// ---------------------------------------------------------------------------
__global__ __launch_bounds__(256) void final_kernel(
    const float* __restrict__ Y, const float* __restrict__ st,
    const float* __restrict__ g, const float* __restrict__ bb,
    const float* __restrict__ w11, float* __restrict__ out) {
  const int b = blockIdx.x;
  const int tid = threadIdx.x;
  __shared__ float tch[408];
  for (int c = tid; c < 408; c += 256) {
    float m = st[c] * (1.f / 256.f);
    float v = st[512 + c] * (1.f / 256.f) - m * m;
    float sc = g[c] * rsqrtf(v + EPSBN);
    float bi = bb[c] - m * sc;
    const float* p = Y + ((size_t)b * 408 + c) * 32;
    float ssum = 0.f;
#pragma unroll
    for (int l = 0; l < 32; ++l) ssum += fmaxf(p[l] * sc + bi, 0.f);
    tch[c] = ssum * (1.f / 32.f);
  }
  __syncthreads();
  if (tid < 10) {
    float ssum = 0.f;
    for (int c = 0; c < 408; ++c) ssum += w11[tid * 408 + c] * tch[c];
    out[b * 10 + tid] = ssum;
  }
}

// ---------------------------------------------------------------------------
extern "C" void kernel_launch(void* const* d_in, const int* in_sizes, int n_in,
                              void* d_out, int out_size, void* d_ws,
                              size_t ws_size, hipStream_t stream) {
  const float* x = (const float*)d_in[0];
  const float* w1 = (const float*)d_in[1];
  const float* w2 = (const float*)d_in[2];
  const float* w3 = (const float*)d_in[3];
  const float* w4 = (const float*)d_in[4];
  const float* w5 = (const float*)d_in[5];
  const float* w6 = (const float*)d_in[6];
  const float* w7 = (const float*)d_in[7];
  const float* w8 = (const float*)d_in[8];
  const float* w9 = (const float*)d_in[9];
  const float* w10 = (const float*)d_in[10];
  const float* w11 = (const float*)d_in[11];
  const float* gg[11];
  const float* bbv[11];
  for (int i = 1; i <= 10; ++i) {
    gg[i] = (const float*)d_in[12 + 2 * (i - 1)];
    bbv[i] = (const float*)d_in[12 + 2 * (i - 1) + 1];
  }

  float* ws = (float*)d_ws;
  const size_t AR0 = 0;
  const size_t AR1 = 30081024;
  const size_t STATS = 37601280;
  float* y1 = ws + AR0;
  float* xpad = ws + AR1;
  short* apk1 = (short*)(ws + AR1 + 460800);
  // bf16 activation buffers (ushort), aliasing AR1 as lifetimes permit
  unsigned short* z1b = (unsigned short*)(ws + AR1);           // 7.52M ush
  unsigned short* a3b = (unsigned short*)(ws + AR1);           // 5.85M ush
  unsigned short* z3b = (unsigned short*)(ws + AR1);           // 1.46M ush
  unsigned short* a5b = (unsigned short*)(ws + AR1 + 1500000); // 2.09M ush
  float* z5 = ws + AR1;
  float* a6 = ws + AR1 + 522240;
  float* a7 = ws + AR1 + 1148928;
  float* z8 = ws + AR1;
  float* a9 = ws + AR1 + 1775616;
  float* y2 = ws + AR0;
  float* y3 = ws + AR0 + 5849088;
  float* y4 = ws + AR0;
  float* y5 = ws + AR0 + 2088960;
  float* y6 = ws + AR0;
  float* y7 = ws + AR0 + 626688;
  float* y8 = ws + AR0 + 1253376;
  float* y9 = ws + AR0;
  float* y10 = ws + AR0 + 104448;
  short* apk2 = (short*)(ws + 12000000);
  short* apk3 = apk2 + 7 * 2 * 64 * 512;
  short* apk4 = apk3 + 7 * 2 * 64 * 192;
  short* apk5 = apk4 + 5 * 2 * 128 * 512;
  float* st[11];
  for (int i = 1; i <= 10; ++i) st[i] = ws + STATS + (size_t)(i - 1) * 1024;

  hipMemsetAsync((void*)(ws + STATS), 0, 10 * 1024 * sizeof(float), stream);

  // ---- pad x, pack w1, MFMA lift (+ split stats1 pass)
  pad_x_kernel<<<(8 * PROW + 255) / 256, 256, 0, stream>>>(x, xpad);
  pack_w1_kernel<<<(9 * 64 * 96 + 255) / 256, 256, 0, stream>>>(w1, apk1);
  lift_mfma_kernel<<<dim3(512, 9, 8), 256, 0, stream>>>(xpad, apk1, y1);
  stats_kernel<<<dim3(51, 8, 8), 256, 0, stream>>>(y1, st[1], 51, 9 * 8192, 8);
  {
    unsigned int tot = 8u * 51 * 9 * 2048;
    bnrelu_pool_bf16_kernel<<<(tot + 255) / 256, 256, 0, stream>>>(
        y1, st[1], gg[1], bbv[1], z1b, 51, 9, 8192, 1.f / 589824.f, tot);
  }
  // ---- per-s weight packs (y1 dead)
  pack_w2_kernel<<<(7 * 64 * 512 + 255) / 256, 256, 0, stream>>>(
      w2, apk2, 51, 459, 512, 64, 7, 9);
  pack_w2_kernel<<<(7 * 64 * 192 + 255) / 256, 256, 0, stream>>>(
      w3, apk3, 51, 153, 192, 64, 7, 3);
  pack_w2_kernel<<<(5 * 128 * 512 + 255) / 256, 256, 0, stream>>>(
      w4, apk4, 102, 459, 512, 128, 5, 9);
  pack_w2_kernel<<<(5 * 128 * 320 + 255) / 256, 256, 0, stream>>>(
      w5, apk5, 102, 306, 320, 128, 5, 3);
  // ---- gg2: 51->51, H 9->7, L=2048
  gg_mfma5_kernel<3, 64><<<dim3(32, 7, 8), 256, 0, stream>>>(
      z1b, apk2, y2, st[2], 51, 51, 9, 2048, 32, 459, 512, 64);
  {
    unsigned int tot = 8u * 51 * 7 * 2048;
    bnrelu_bf16_kernel<<<(tot + 255) / 256, 256, 0, stream>>>(
        y2, st[2], gg[2], bbv[2], a3b, 51, 7 * 2048, 1.f / 114688.f, tot);
  }
  // ---- gg3: 51->51, H7, L=2048
  gg_mfma5_kernel<1, 64><<<dim3(32, 7, 8), 256, 0, stream>>>(
      a3b, apk3, y3, st[3], 51, 51, 7, 2048, 32, 153, 192, 64);
  {
    unsigned int tot = 8u * 51 * 7 * 512;
    bnrelu_pool_bf16_kernel<<<(tot + 255) / 256, 256, 0, stream>>>(
        y3, st[3], gg[3], bbv[3], z3b, 51, 7, 2048, 1.f / 114688.f, tot);
  }
  // ---- gg4: 51->102, H 7->5, L=512
  gg_mfma5_kernel<3, 32><<<dim3(32, 5, 8), 256, 0, stream>>>(
      z3b, apk4, y4, st[4], 51, 102, 7, 512, 16, 459, 512, 128);
  {
    unsigned int tot = 8u * 102 * 5 * 512;
    bnrelu_bf16_kernel<<<(tot + 255) / 256, 256, 0, stream>>>(
        y4, st[4], gg[4], bbv[4], a5b, 102, 5 * 512, 1.f / 20480.f, tot);
  }
  // ---- gg5: 102->102, H5, L=512
  gg_mfma5_kernel<1, 32><<<dim3(32, 5, 8), 256, 0, stream>>>(
      a5b, apk5, y5, st[5], 102, 102, 5, 512, 16, 306, 320, 128);
  {
    unsigned int tot = 8u * 102 * 5 * 128;
    bnrelu_pool_kernel<<<(tot + 255) / 256, 256, 0, stream>>>(
        y5, st[5], gg[5], bbv[5], z5, 102, 5, 512, 1.f / 20480.f, tot);
  }
  // ---- gg6/7/8: K-split x3 tails (atomic accumulate, separate stats)
  hipMemsetAsync((void*)y6, 0, 3 * 626688 * sizeof(float), stream);
  gg_tail2_kernel<3, 128, 2><<<dim3(102, 9, 8), 256, 0, stream>>>(
      z5, w6, y6, 102, 204, 5, 3, 34);
  stats_kernel<<<dim3(204, 8, 1), 256, 0, stream>>>(y6, st[6], 204, 384, 1);
  {
    unsigned int tot = 8u * 204 * 3 * 128;
    bnrelu_kernel<<<(tot + 255) / 256, 256, 0, stream>>>(
        y6, st[6], gg[6], bbv[6], a6, 204, 3 * 128, 1.f / 3072.f, tot);
  }
  gg_tail2_kernel<1, 128, 2><<<dim3(102, 9, 8), 256, 0, stream>>>(
      a6, w7, y7, 204, 204, 3, 3, 68);
  stats_kernel<<<dim3(204, 8, 1), 256, 0, stream>>>(y7, st[7], 204, 384, 1);
  {
    unsigned int tot = 8u * 204 * 3 * 128;
    bnrelu_kernel<<<(tot + 255) / 256, 256, 0, stream>>>(
        y7, st[7], gg[7], bbv[7], a7, 204, 3 * 128, 1.f / 3072.f, tot);
  }
  gg_tail2_kernel<1, 128, 2><<<dim3(102, 9, 8), 256, 0, stream>>>(
      a7, w8, y8, 204, 204, 3, 3, 68);
  stats_kernel<<<dim3(204, 8, 1), 256, 0, stream>>>(y8, st[8], 204, 384, 1);
  {
    unsigned int tot = 8u * 204 * 3 * 32;
    bnrelu_pool_kernel<<<(tot + 255) / 256, 256, 0, stream>>>(
        y8, st[8], gg[8], bbv[8], z8, 204, 3, 128, 1.f / 3072.f, tot);
  }
  // ---- gg9: 204->408, H 3->1, L=32 (K-split x4)
  hipMemsetAsync((void*)y9, 0, 2 * 104448 * sizeof(float), stream);
  gg_tail2_kernel<3, 32, 8><<<dim3(51, 4, 8), 256, 0, stream>>>(
      z8, w9, y9, 204, 408, 3, 4, 51);
  stats_kernel<<<dim3(408, 8, 1), 256, 0, stream>>>(y9, st[9], 408, 32, 1);
  {
    unsigned int tot = 8u * 408 * 32;
    bnrelu_kernel<<<(tot + 255) / 256, 256, 0, stream>>>(
        y9, st[9], gg[9], bbv[9], a9, 408, 32, 1.f / 256.f, tot);
  }
  // ---- gg10: 408->408, H1, L=32 (K-split x4)
  gg_tail2_kernel<1, 32, 8><<<dim3(51, 4, 8), 256, 0, stream>>>(
      a9, w10, y10, 408, 408, 1, 4, 102);
  stats_kernel<<<dim3(408, 8, 1), 256, 0, stream>>>(y10, st[10], 408, 32, 1);
  // ---- final
  final_kernel<<<dim3(8), 256, 0, stream>>>(y10, st[10], gg[10], bbv[10], w11,
                                            (float*)d_out);
}